// Round 1
// baseline (1507.007 us; speedup 1.0000x reference)
//
#include <hip/hip_runtime.h>
#include <hip/hip_bf16.h>
#include <math.h>

// Problem constants
#define Bn 4
#define Ln 1024
#define Vn 64
#define Dn 256
#define Hn 4
#define DKn 64
#define NLn 4
#define Mn 20
#define FFn 1024
#define NTOK (Bn * Ln)   // 4096

// ---------------------------------------------------------------------------
// embed: h[n][d] = sum_v x[n][v] * emb[v][d]
__global__ __launch_bounds__(256) void embed_k(const float* __restrict__ X,
                                               const float* __restrict__ E,
                                               float* __restrict__ Hf) {
    __shared__ float xs[Vn];
    int n = blockIdx.x;
    int d = threadIdx.x;
    if (threadIdx.x < Vn) xs[threadIdx.x] = X[n * Vn + threadIdx.x];
    __syncthreads();
    float s = 0.f;
#pragma unroll
    for (int v = 0; v < Vn; ++v) s += xs[v] * E[v * Dn + d];
    Hf[n * Dn + d] = s;
}

// ---------------------------------------------------------------------------
// relbias: biask[l][h][dist] = rel_k[l][idx(dist)][h]  (dist in [0,1024))
__global__ __launch_bounds__(256) void relbias_k(const float* __restrict__ rk,
                                                 const float* __restrict__ rb,
                                                 float* __restrict__ bkT,
                                                 float* __restrict__ bbT) {
    int tid = blockIdx.x * 256 + threadIdx.x;   // < NL*H*1024 = 16384
    int dist = tid & 1023;
    int hh = (tid >> 10) & 3;
    int l = tid >> 12;
    float dd = (float)dist;
    if (dist > Mn) dd = (float)Mn + log2f((float)(dist - Mn));
    if (dd > 2.0f * Mn) dd = 2.0f * Mn;
    int idx = (int)dd;   // truncation == floor (non-negative)
    bkT[tid] = rk[(l * (2 * Mn + 1) + idx) * Hn + hh];
    bbT[tid] = rb[(l * (2 * Mn + 1) + idx) * Hn + hh];
}

// ---------------------------------------------------------------------------
// Generic tiled fp32 GEMM: C[m][n] = act(sum_k A[m][k]*W[k][n] + bias[n])
// act: 0 = none, 1 = exact gelu
#define BM 64
#define BN 64
#define BK 16
#define LDST 72   // padded LDS stride (floats); 72*4B=288B, 16B aligned
__global__ __launch_bounds__(256) void gemm_bias_act(
    const float* __restrict__ A, const float* __restrict__ W,
    const float* __restrict__ bias, float* __restrict__ C,
    int M, int N, int K, int act) {
    __shared__ __align__(16) float As[BK * LDST];
    __shared__ __align__(16) float Bs[BK * LDST];
    int t = threadIdx.x;
    int tx = t & 15, ty = t >> 4;
    int mBase = blockIdx.y * BM, nBase = blockIdx.x * BN;
    float acc[4][4] = {{0.f}};
    for (int k0 = 0; k0 < K; k0 += BK) {
#pragma unroll
        for (int i = 0; i < 4; ++i) {
            int e = t + 256 * i;            // A tile: 64m x 16k
            int m = e >> 4, kk = e & 15;
            As[kk * LDST + m] = A[(size_t)(mBase + m) * K + k0 + kk];
        }
#pragma unroll
        for (int i = 0; i < 4; ++i) {
            int e = t + 256 * i;            // B tile: 16k x 64n
            int kk = e >> 6, n = e & 63;
            Bs[kk * LDST + n] = W[(size_t)(k0 + kk) * N + nBase + n];
        }
        __syncthreads();
#pragma unroll
        for (int kk = 0; kk < BK; ++kk) {
            float4 a4 = *(const float4*)&As[kk * LDST + ty * 4];
            float4 b4 = *(const float4*)&Bs[kk * LDST + tx * 4];
            acc[0][0] += a4.x * b4.x; acc[0][1] += a4.x * b4.y;
            acc[0][2] += a4.x * b4.z; acc[0][3] += a4.x * b4.w;
            acc[1][0] += a4.y * b4.x; acc[1][1] += a4.y * b4.y;
            acc[1][2] += a4.y * b4.z; acc[1][3] += a4.y * b4.w;
            acc[2][0] += a4.z * b4.x; acc[2][1] += a4.z * b4.y;
            acc[2][2] += a4.z * b4.z; acc[2][3] += a4.z * b4.w;
            acc[3][0] += a4.w * b4.x; acc[3][1] += a4.w * b4.y;
            acc[3][2] += a4.w * b4.z; acc[3][3] += a4.w * b4.w;
        }
        __syncthreads();
    }
    float4 bs = *(const float4*)&bias[nBase + tx * 4];
    float bb[4] = {bs.x, bs.y, bs.z, bs.w};
#pragma unroll
    for (int i = 0; i < 4; ++i) {
        int m = mBase + ty * 4 + i;
        float4 outv;
        float* ov = (float*)&outv;
#pragma unroll
        for (int j = 0; j < 4; ++j) {
            float vv = acc[i][j] + bb[j];
            if (act == 1) vv = vv * 0.5f * (1.0f + erff(vv * 0.7071067811865475f));
            ov[j] = vv;
        }
        *(float4*)&C[(size_t)m * N + nBase + tx * 4] = outv;
    }
}

// ---------------------------------------------------------------------------
// Fused attention for one layer, per (b, h, 8-row tile).
// 256 threads: r = t>>5 in [0,8) row, cg = t&31 col group (32 cols each).
#define ROWS 8
#define KVST 68   // K/V chunk LDS stride
__global__ __launch_bounds__(256) void attn_fused(
    const float* __restrict__ Q, const float* __restrict__ Kb,
    const float* __restrict__ Vb, const float* __restrict__ bkTab,
    const float* __restrict__ bbTab, float* __restrict__ ctx,
    float* __restrict__ avg, int first) {
    __shared__ __align__(16) float kv[64 * KVST];
    __shared__ float sc_lds[ROWS * Ln];
    __shared__ float bk_l[Ln];
    __shared__ float bb_l[Ln];
    __shared__ float qs[ROWS * KVST];

    int t = threadIdx.x;
    int cg = t & 31, r = t >> 5;
    int b = blockIdx.z, hh = blockIdx.y;
    int i0 = blockIdx.x * ROWS;
    int i = i0 + r;

    // stage bias tables (4KB each) + q tile
#pragma unroll
    for (int ii = 0; ii < 4; ++ii) {
        bk_l[t + 256 * ii] = bkTab[hh * Ln + t + 256 * ii];
        bb_l[t + 256 * ii] = bbTab[hh * Ln + t + 256 * ii];
    }
#pragma unroll
    for (int ii = 0; ii < 2; ++ii) {
        int e = t + 256 * ii;   // 512 = 8 rows x 64
        int rr = e >> 6, d = e & 63;
        qs[rr * KVST + d] = Q[((size_t)(b * Ln + i0 + rr)) * Dn + hh * DKn + d];
    }
    __syncthreads();

    float qreg[64];
#pragma unroll
    for (int d = 0; d < 64; ++d) qreg[d] = qs[r * KVST + d];

    // ---- score phase: raw dots into sc_lds -------------------------------
    for (int c = 0; c < 16; ++c) {
        __syncthreads();
#pragma unroll
        for (int ii = 0; ii < 16; ++ii) {
            int e = t + 256 * ii;         // 4096 = 64 rows x 64 dims
            int j = e >> 6, d = e & 63;
            kv[j * KVST + d] = Kb[((size_t)(b * Ln + c * 64 + j)) * Dn + hh * DKn + d];
        }
        __syncthreads();
#pragma unroll
        for (int s = 0; s < 2; ++s) {
            int jl = cg + 32 * s;
            const float4* kvp = (const float4*)&kv[jl * KVST];
            float acc = 0.f;
#pragma unroll
            for (int d4 = 0; d4 < 16; ++d4) {
                float4 k4 = kvp[d4];
                acc += qreg[4 * d4 + 0] * k4.x + qreg[4 * d4 + 1] * k4.y
                     + qreg[4 * d4 + 2] * k4.z + qreg[4 * d4 + 3] * k4.w;
            }
            sc_lds[r * Ln + c * 64 + jl] = acc;   // self-read later, no sync needed
        }
    }

    // ---- bias + softmax (thread owns cols j = cg + 32*jj) -----------------
    float scv[32];
#pragma unroll
    for (int jj = 0; jj < 32; ++jj) {
        int j = cg + 32 * jj;
        float raw = sc_lds[r * Ln + j];
        int dist = (i > j) ? (i - j) : (j - i);
        scv[jj] = raw * 0.125f * bk_l[dist] + bb_l[dist];
    }
    float mx = scv[0];
#pragma unroll
    for (int jj = 1; jj < 32; ++jj) mx = fmaxf(mx, scv[jj]);
#pragma unroll
    for (int m = 1; m < 32; m <<= 1) mx = fmaxf(mx, __shfl_xor(mx, m, 64));
    float sum = 0.f;
#pragma unroll
    for (int jj = 0; jj < 32; ++jj) {
        float p = __expf(scv[jj] - mx);
        scv[jj] = p;
        sum += p;
    }
#pragma unroll
    for (int m = 1; m < 32; m <<= 1) sum += __shfl_xor(sum, m, 64);
    float inv = 1.0f / sum;
#pragma unroll
    for (int jj = 0; jj < 32; ++jj) {
        int j = cg + 32 * jj;
        float a = scv[jj] * inv;
        sc_lds[r * Ln + j] = a;
        size_t oidx = ((size_t)((b * Hn + hh) * Ln + i)) * Ln + j;
        if (first) avg[oidx] = 0.25f * a;
        else       avg[oidx] += 0.25f * a;
    }

    // ---- PV phase ----------------------------------------------------------
    float o[64];
#pragma unroll
    for (int d = 0; d < 64; ++d) o[d] = 0.f;
    for (int c = 0; c < 16; ++c) {
        __syncthreads();
#pragma unroll
        for (int ii = 0; ii < 16; ++ii) {
            int e = t + 256 * ii;
            int j = e >> 6, d = e & 63;
            kv[j * KVST + d] = Vb[((size_t)(b * Ln + c * 64 + j)) * Dn + hh * DKn + d];
        }
        __syncthreads();
#pragma unroll
        for (int s = 0; s < 2; ++s) {
            int jl = cg + 32 * s;
            float a = sc_lds[r * Ln + c * 64 + jl];
            const float4* vp = (const float4*)&kv[jl * KVST];
#pragma unroll
            for (int d4 = 0; d4 < 16; ++d4) {
                float4 v4 = vp[d4];
                o[4 * d4 + 0] += a * v4.x;
                o[4 * d4 + 1] += a * v4.y;
                o[4 * d4 + 2] += a * v4.z;
                o[4 * d4 + 3] += a * v4.w;
            }
        }
    }

    // ---- reduce-scatter across the 32 cg lanes (static indices only) ------
#define RS_STEP(MASK, SZ)                                        \
    do {                                                         \
        bool hi_ = (cg & MASK) != 0;                             \
        _Pragma("unroll")                                        \
        for (int ii = 0; ii < SZ; ++ii) {                        \
            float snd = hi_ ? o[ii] : o[ii + SZ];                \
            float rcv = __shfl_xor(snd, MASK, 64);               \
            o[ii] = (hi_ ? o[ii + SZ] : o[ii]) + rcv;            \
        }                                                        \
    } while (0)
    RS_STEP(16, 32);
    RS_STEP(8, 16);
    RS_STEP(4, 8);
    RS_STEP(2, 4);
    RS_STEP(1, 2);
#undef RS_STEP
    // lane cg now holds fully-reduced o for d = 2cg, 2cg+1
    float2 o2 = make_float2(o[0], o[1]);
    *(float2*)&ctx[((size_t)(b * Ln + i)) * Dn + hh * DKn + 2 * cg] = o2;
}

// ---------------------------------------------------------------------------
// LayerNorm over last dim (256); one wave per row, 4 rows per block. In-place OK.
__global__ __launch_bounds__(256) void layernorm_k(const float* __restrict__ X,
                                                   const float* __restrict__ g,
                                                   const float* __restrict__ bta,
                                                   float* __restrict__ Y) {
    int w = threadIdx.x >> 6, lane = threadIdx.x & 63;
    int row = blockIdx.x * 4 + w;
    const float* xr = X + (size_t)row * Dn;
    float x[4];
#pragma unroll
    for (int ii = 0; ii < 4; ++ii) x[ii] = xr[lane + 64 * ii];
    float s = x[0] + x[1] + x[2] + x[3];
#pragma unroll
    for (int m = 1; m < 64; m <<= 1) s += __shfl_xor(s, m, 64);
    float mu = s * (1.0f / 256.0f);
    float vs = 0.f;
#pragma unroll
    for (int ii = 0; ii < 4; ++ii) {
        float d = x[ii] - mu;
        vs += d * d;
    }
#pragma unroll
    for (int m = 1; m < 64; m <<= 1) vs += __shfl_xor(vs, m, 64);
    float rs = rsqrtf(vs * (1.0f / 256.0f) + 1e-5f);
#pragma unroll
    for (int ii = 0; ii < 4; ++ii) {
        int d = lane + 64 * ii;
        Y[(size_t)row * Dn + d] = (x[ii] - mu) * rs * g[d] + bta[d];
    }
}

// ---------------------------------------------------------------------------
// out0[b][d] = mean over L of h[b][i][d]
__global__ __launch_bounds__(256) void mean_rows_k(const float* __restrict__ Hf,
                                                   float* __restrict__ out) {
    int b = blockIdx.x, d = threadIdx.x;
    float s = 0.f;
    for (int i = 0; i < Ln; ++i) s += Hf[((size_t)(b * Ln + i)) * Dn + d];
    out[b * Dn + d] = s * (1.0f / (float)Ln);
}

// ---------------------------------------------------------------------------
extern "C" void kernel_launch(void* const* d_in, const int* in_sizes, int n_in,
                              void* d_out, int out_size, void* d_ws, size_t ws_size,
                              hipStream_t stream) {
    const float* x    = (const float*)d_in[0];
    const float* emb  = (const float*)d_in[1];
    const float* Wq   = (const float*)d_in[2];
    const float* bq   = (const float*)d_in[3];
    const float* Wk   = (const float*)d_in[4];
    const float* bk   = (const float*)d_in[5];
    const float* Wv   = (const float*)d_in[6];
    const float* bv   = (const float*)d_in[7];
    const float* Wo   = (const float*)d_in[8];
    const float* bo   = (const float*)d_in[9];
    const float* rk   = (const float*)d_in[10];
    const float* rb   = (const float*)d_in[11];
    const float* ln1g = (const float*)d_in[12];
    const float* ln1b = (const float*)d_in[13];
    const float* W1   = (const float*)d_in[14];
    const float* b1   = (const float*)d_in[15];
    const float* W2   = (const float*)d_in[16];
    const float* b2   = (const float*)d_in[17];
    const float* ln2g = (const float*)d_in[18];
    const float* ln2b = (const float*)d_in[19];

    float* out = (float*)d_out;
    float* avg = out + Bn * Dn;   // avg_attn region, [B,H,L,L]

    char* ws = (char*)d_ws;
    const size_t MB = 1024 * 1024;
    float* hbuf = (float*)(ws + 0 * MB);
    float* qb   = (float*)(ws + 4 * MB);
    float* kbuf = (float*)(ws + 8 * MB);
    float* vbuf = (float*)(ws + 12 * MB);
    float* ctx  = (float*)(ws + 16 * MB);
    float* tmp  = (float*)(ws + 20 * MB);
    float* ff   = (float*)(ws + 24 * MB);   // 16 MB
    float* bkT  = (float*)(ws + 40 * MB);
    float* bbT  = (float*)(ws + 40 * MB + 65536);

    embed_k<<<NTOK, 256, 0, stream>>>(x, emb, hbuf);
    relbias_k<<<64, 256, 0, stream>>>(rk, rb, bkT, bbT);

    for (int l = 0; l < NLn; ++l) {
        const int WQK = Dn * Hn * DKn;   // 65536
        gemm_bias_act<<<dim3(4, 64), 256, 0, stream>>>(
            hbuf, Wq + l * WQK, bq + l * 256, qb, NTOK, 256, 256, 0);
        gemm_bias_act<<<dim3(4, 64), 256, 0, stream>>>(
            hbuf, Wk + l * WQK, bk + l * 256, kbuf, NTOK, 256, 256, 0);
        gemm_bias_act<<<dim3(4, 64), 256, 0, stream>>>(
            hbuf, Wv + l * WQK, bv + l * 256, vbuf, NTOK, 256, 256, 0);
        attn_fused<<<dim3(Ln / ROWS, Hn, Bn), 256, 0, stream>>>(
            qb, kbuf, vbuf, bkT + l * Hn * Ln, bbT + l * Hn * Ln, ctx, avg,
            (l == 0) ? 1 : 0);
        gemm_bias_act<<<dim3(4, 64), 256, 0, stream>>>(
            ctx, Wo + l * WQK, bo + l * 256, tmp, NTOK, 256, 256, 0);
        layernorm_k<<<NTOK / 4, 256, 0, stream>>>(
            tmp, ln1g + l * 256, ln1b + l * 256, tmp);
        gemm_bias_act<<<dim3(16, 64), 256, 0, stream>>>(
            tmp, W1 + l * Dn * FFn, b1 + l * FFn, ff, NTOK, FFn, 256, 1);
        gemm_bias_act<<<dim3(4, 64), 256, 0, stream>>>(
            ff, W2 + l * FFn * Dn, b2 + l * 256, hbuf, NTOK, 256, FFn, 0);
        layernorm_k<<<NTOK / 4, 256, 0, stream>>>(
            hbuf, ln2g + l * 256, ln2b + l * 256, hbuf);
    }
    mean_rows_k<<<Bn, 256, 0, stream>>>(hbuf, out);
}

// Round 2
// 1455.980 us; speedup vs baseline: 1.0350x; 1.0350x over previous
//
#include <hip/hip_runtime.h>
#include <hip/hip_bf16.h>
#include <math.h>

// Problem constants
#define Bn 4
#define Ln 1024
#define Vn 64
#define Dn 256
#define Hn 4
#define DKn 64
#define NLn 4
#define Mn 20
#define FFn 1024
#define NTOK (Bn * Ln)   // 4096
#define QKVW 768         // fused q|k|v width

typedef __attribute__((ext_vector_type(8))) short bf16x8;
typedef __attribute__((ext_vector_type(4))) float f32x4;

__device__ __forceinline__ ushort f2b(float f) {   // fp32 -> bf16 RNE
    uint u = __float_as_uint(f);
    u += 0x7fff + ((u >> 16) & 1);
    return (ushort)(u >> 16);
}
__device__ __forceinline__ float b2f(ushort u) {   // exact
    return __uint_as_float(((uint)u) << 16);
}

// ---------------------------------------------------------------------------
__global__ __launch_bounds__(256) void embed_k(const float* __restrict__ X,
                                               const float* __restrict__ E,
                                               ushort* __restrict__ Hb) {
    __shared__ float xs[Vn];
    int n = blockIdx.x, d = threadIdx.x;
    if (threadIdx.x < Vn) xs[threadIdx.x] = X[n * Vn + threadIdx.x];
    __syncthreads();
    float s = 0.f;
#pragma unroll
    for (int v = 0; v < Vn; ++v) s += xs[v] * E[v * Dn + d];
    Hb[(size_t)n * Dn + d] = f2b(s);
}

// ---------------------------------------------------------------------------
__global__ __launch_bounds__(256) void relbias_k(const float* __restrict__ rk,
                                                 const float* __restrict__ rb,
                                                 float* __restrict__ bkT,
                                                 float* __restrict__ bbT) {
    int tid = blockIdx.x * 256 + threadIdx.x;   // < NL*H*1024
    int dist = tid & 1023;
    int hh = (tid >> 10) & 3;
    int l = tid >> 12;
    float dd = (float)dist;
    if (dist > Mn) dd = (float)Mn + log2f((float)(dist - Mn));
    if (dd > 2.0f * Mn) dd = 2.0f * Mn;
    int idx = (int)dd;
    bkT[tid] = rk[(l * (2 * Mn + 1) + idx) * Hn + hh];
    bbT[tid] = rb[(l * (2 * Mn + 1) + idx) * Hn + hh];
}

// ---------------------------------------------------------------------------
__global__ __launch_bounds__(256) void prep_bias(const float* __restrict__ bq,
                                                 const float* __restrict__ bk,
                                                 const float* __restrict__ bv,
                                                 float* __restrict__ bqkv) {
    int idx = blockIdx.x * 256 + threadIdx.x;   // < NL*768
    int l = idx / QKVW, r = idx - l * QKVW;
    float v;
    if (r < 256)      v = bq[l * 256 + r];
    else if (r < 512) v = bk[l * 256 + r - 256];
    else              v = bv[l * 256 + r - 512];
    bqkv[idx] = v;
}

// ---------------------------------------------------------------------------
// Transpose + fp32->bf16: dst[c][r] = src[r][c]; grid.z indexes layers.
__global__ __launch_bounds__(256) void transpose_cvt(
    const float* __restrict__ src, ushort* __restrict__ dst,
    int R, int C, int srcLS, int dstLS) {
    __shared__ float s[32][33];
    src += (size_t)blockIdx.z * srcLS;
    dst += (size_t)blockIdx.z * dstLS;
    int r0 = blockIdx.y * 32, c0 = blockIdx.x * 32;
    int tx = threadIdx.x & 31, ty = threadIdx.x >> 5;   // ty in [0,8)
#pragma unroll
    for (int ii = 0; ii < 4; ++ii)
        s[ty + 8 * ii][tx] = src[(size_t)(r0 + ty + 8 * ii) * C + c0 + tx];
    __syncthreads();
#pragma unroll
    for (int ii = 0; ii < 4; ++ii)
        dst[(size_t)(c0 + ty + 8 * ii) * R + r0 + tx] = f2b(s[tx][ty + 8 * ii]);
}

// ---------------------------------------------------------------------------
// bf16 MFMA GEMM: C[m][n] = act(sum_k A[m][k]*Bt[n][k] + bias[n]), C bf16.
// 64x64 tile, 4 waves (2x2 of 32x32), K-step 32, padded LDS stride 40.
#define GST 40
__global__ __launch_bounds__(256) void gemm_mfma(
    const ushort* __restrict__ A, const ushort* __restrict__ Bt,
    const float* __restrict__ bias, ushort* __restrict__ C,
    int M, int N, int K, int act) {
    __shared__ __align__(16) ushort As[64 * GST];
    __shared__ __align__(16) ushort Bs[64 * GST];
    int t = threadIdx.x;
    int lane = t & 63, w = t >> 6;
    int wm = w >> 1, wn = w & 1;
    int l15 = lane & 15, lg = lane >> 4;
    int mBase = blockIdx.y * 64, nBase = blockIdx.x * 64;
    int lrow = t >> 2, lkc = (t & 3) * 8;
    const ushort* Ap = A + (size_t)(mBase + lrow) * K + lkc;
    const ushort* Bp = Bt + (size_t)(nBase + lrow) * K + lkc;
    f32x4 acc[2][2] = {};
    for (int k0 = 0; k0 < K; k0 += 32) {
        uint4 av = *(const uint4*)(Ap + k0);
        uint4 bv = *(const uint4*)(Bp + k0);
        __syncthreads();                       // protect prior ds_reads
        *(uint4*)&As[lrow * GST + lkc] = av;
        *(uint4*)&Bs[lrow * GST + lkc] = bv;
        __syncthreads();
        bf16x8 a0 = *(const bf16x8*)&As[(wm * 32 + l15) * GST + lg * 8];
        bf16x8 a1 = *(const bf16x8*)&As[(wm * 32 + 16 + l15) * GST + lg * 8];
        bf16x8 b0 = *(const bf16x8*)&Bs[(wn * 32 + l15) * GST + lg * 8];
        bf16x8 b1 = *(const bf16x8*)&Bs[(wn * 32 + 16 + l15) * GST + lg * 8];
        acc[0][0] = __builtin_amdgcn_mfma_f32_16x16x32_bf16(a0, b0, acc[0][0], 0, 0, 0);
        acc[0][1] = __builtin_amdgcn_mfma_f32_16x16x32_bf16(a0, b1, acc[0][1], 0, 0, 0);
        acc[1][0] = __builtin_amdgcn_mfma_f32_16x16x32_bf16(a1, b0, acc[1][0], 0, 0, 0);
        acc[1][1] = __builtin_amdgcn_mfma_f32_16x16x32_bf16(a1, b1, acc[1][1], 0, 0, 0);
    }
#pragma unroll
    for (int ni = 0; ni < 2; ++ni) {
        int col = nBase + wn * 32 + ni * 16 + l15;
        float bc = bias[col];
#pragma unroll
        for (int mi = 0; mi < 2; ++mi) {
            int rb = mBase + wm * 32 + mi * 16 + lg * 4;
#pragma unroll
            for (int j = 0; j < 4; ++j) {
                float v = acc[mi][ni][j] + bc;
                if (act) v = v * 0.5f * (1.0f + erff(v * 0.7071067811865475f));
                C[(size_t)(rb + j) * N + col] = f2b(v);
            }
        }
    }
}

// ---------------------------------------------------------------------------
// Fused attention, one layer, per (b, h, 8-row tile). Scores live in registers.
#define ROWS 8
#define KVST 68
__global__ __launch_bounds__(256) void attn_fused(
    const ushort* __restrict__ qkv, const float* __restrict__ bkTab,
    const float* __restrict__ bbTab, ushort* __restrict__ ctx,
    float* __restrict__ avg, int first) {
    __shared__ __align__(16) float kv[64 * KVST];
    __shared__ float bk_l[Ln];
    __shared__ float bb_l[Ln];
    __shared__ float qs[ROWS * KVST];

    int t = threadIdx.x;
    int cg = t & 31, r = t >> 5;
    int b = blockIdx.z, hh = blockIdx.y;
    int i0 = blockIdx.x * ROWS, i = i0 + r;

#pragma unroll
    for (int ii = 0; ii < 4; ++ii) {
        bk_l[t + 256 * ii] = bkTab[hh * Ln + t + 256 * ii];
        bb_l[t + 256 * ii] = bbTab[hh * Ln + t + 256 * ii];
    }
#pragma unroll
    for (int ii = 0; ii < 2; ++ii) {
        int e = t + 256 * ii;
        int rr = e >> 6, d = e & 63;
        qs[rr * KVST + d] = b2f(qkv[(size_t)(b * Ln + i0 + rr) * QKVW + hh * DKn + d]);
    }
    __syncthreads();

    float qreg[64];
#pragma unroll
    for (int d = 0; d < 64; ++d) qreg[d] = qs[r * KVST + d];

    float scv[32];
    // ---- score phase (K section at col offset Dn) --------------------------
#pragma unroll
    for (int c = 0; c < 16; ++c) {
        __syncthreads();
#pragma unroll
        for (int ii = 0; ii < 2; ++ii) {
            int e = t + 256 * ii;
            int j = e >> 3, dc = (e & 7) * 8;
            uint4 raw = *(const uint4*)&qkv[(size_t)(b * Ln + c * 64 + j) * QKVW + Dn + hh * DKn + dc];
            const ushort* rp = (const ushort*)&raw;
            *(float4*)&kv[j * KVST + dc] =
                make_float4(b2f(rp[0]), b2f(rp[1]), b2f(rp[2]), b2f(rp[3]));
            *(float4*)&kv[j * KVST + dc + 4] =
                make_float4(b2f(rp[4]), b2f(rp[5]), b2f(rp[6]), b2f(rp[7]));
        }
        __syncthreads();
#pragma unroll
        for (int s = 0; s < 2; ++s) {
            int jl = cg + 32 * s;
            const float4* kp = (const float4*)&kv[jl * KVST];
            float acc = 0.f;
#pragma unroll
            for (int d4 = 0; d4 < 16; ++d4) {
                float4 k4 = kp[d4];
                acc += qreg[4 * d4 + 0] * k4.x + qreg[4 * d4 + 1] * k4.y
                     + qreg[4 * d4 + 2] * k4.z + qreg[4 * d4 + 3] * k4.w;
            }
            int j = c * 64 + jl;
            int dist = (i > j) ? (i - j) : (j - i);
            scv[2 * c + s] = acc * 0.125f * bk_l[dist] + bb_l[dist];
        }
    }

    // ---- softmax in registers ----------------------------------------------
    float mx = scv[0];
#pragma unroll
    for (int jj = 1; jj < 32; ++jj) mx = fmaxf(mx, scv[jj]);
#pragma unroll
    for (int m = 1; m < 32; m <<= 1) mx = fmaxf(mx, __shfl_xor(mx, m, 64));
    float sum = 0.f;
#pragma unroll
    for (int jj = 0; jj < 32; ++jj) {
        float p = __expf(scv[jj] - mx);
        scv[jj] = p;
        sum += p;
    }
#pragma unroll
    for (int m = 1; m < 32; m <<= 1) sum += __shfl_xor(sum, m, 64);
    float inv = 1.0f / sum;
#pragma unroll
    for (int jj = 0; jj < 32; ++jj) {
        float a = scv[jj] * inv;
        scv[jj] = a;
        size_t oidx = ((size_t)((b * Hn + hh) * Ln + i)) * Ln + cg + 32 * jj;
        if (first) avg[oidx] = 0.25f * a;
        else       avg[oidx] += 0.25f * a;
    }

    // ---- PV phase (V section at col offset 2*Dn) ---------------------------
    float o[64];
#pragma unroll
    for (int d = 0; d < 64; ++d) o[d] = 0.f;
#pragma unroll
    for (int c = 0; c < 16; ++c) {
        __syncthreads();
#pragma unroll
        for (int ii = 0; ii < 2; ++ii) {
            int e = t + 256 * ii;
            int j = e >> 3, dc = (e & 7) * 8;
            uint4 raw = *(const uint4*)&qkv[(size_t)(b * Ln + c * 64 + j) * QKVW + 2 * Dn + hh * DKn + dc];
            const ushort* rp = (const ushort*)&raw;
            *(float4*)&kv[j * KVST + dc] =
                make_float4(b2f(rp[0]), b2f(rp[1]), b2f(rp[2]), b2f(rp[3]));
            *(float4*)&kv[j * KVST + dc + 4] =
                make_float4(b2f(rp[4]), b2f(rp[5]), b2f(rp[6]), b2f(rp[7]));
        }
        __syncthreads();
#pragma unroll
        for (int s = 0; s < 2; ++s) {
            float a = scv[2 * c + s];
            const float4* vp = (const float4*)&kv[(cg + 32 * s) * KVST];
#pragma unroll
            for (int d4 = 0; d4 < 16; ++d4) {
                float4 v4 = vp[d4];
                o[4 * d4 + 0] += a * v4.x;
                o[4 * d4 + 1] += a * v4.y;
                o[4 * d4 + 2] += a * v4.z;
                o[4 * d4 + 3] += a * v4.w;
            }
        }
    }

    // ---- reduce-scatter across 32 cg lanes (static indices) ----------------
#define RS_STEP(MASK, SZ)                                        \
    do {                                                         \
        bool hi_ = (cg & MASK) != 0;                             \
        _Pragma("unroll")                                        \
        for (int ii = 0; ii < SZ; ++ii) {                        \
            float snd = hi_ ? o[ii] : o[ii + SZ];                \
            float rcv = __shfl_xor(snd, MASK, 64);               \
            o[ii] = (hi_ ? o[ii + SZ] : o[ii]) + rcv;            \
        }                                                        \
    } while (0)
    RS_STEP(16, 32);
    RS_STEP(8, 16);
    RS_STEP(4, 8);
    RS_STEP(2, 4);
    RS_STEP(1, 2);
#undef RS_STEP
    uint packed = (uint)f2b(o[0]) | ((uint)f2b(o[1]) << 16);
    *(uint*)&ctx[(size_t)(b * Ln + i) * Dn + hh * DKn + 2 * cg] = packed;
}

// ---------------------------------------------------------------------------
__global__ __launch_bounds__(256) void layernorm_k(const ushort* __restrict__ X,
                                                   const float* __restrict__ g,
                                                   const float* __restrict__ bta,
                                                   ushort* __restrict__ Y) {
    int w = threadIdx.x >> 6, lane = threadIdx.x & 63;
    int row = blockIdx.x * 4 + w;
    const ushort* xr = X + (size_t)row * Dn;
    float x[4];
#pragma unroll
    for (int ii = 0; ii < 4; ++ii) x[ii] = b2f(xr[lane + 64 * ii]);
    float s = x[0] + x[1] + x[2] + x[3];
#pragma unroll
    for (int m = 1; m < 64; m <<= 1) s += __shfl_xor(s, m, 64);
    float mu = s * (1.0f / 256.0f);
    float vs = 0.f;
#pragma unroll
    for (int ii = 0; ii < 4; ++ii) {
        float d = x[ii] - mu;
        vs += d * d;
    }
#pragma unroll
    for (int m = 1; m < 64; m <<= 1) vs += __shfl_xor(vs, m, 64);
    float rs = rsqrtf(vs * (1.0f / 256.0f) + 1e-5f);
#pragma unroll
    for (int ii = 0; ii < 4; ++ii) {
        int d = lane + 64 * ii;
        Y[(size_t)row * Dn + d] = f2b((x[ii] - mu) * rs * g[d] + bta[d]);
    }
}

// ---------------------------------------------------------------------------
__global__ __launch_bounds__(256) void mean_rows_k(const ushort* __restrict__ Hb,
                                                   float* __restrict__ out) {
    int b = blockIdx.x, d = threadIdx.x;
    float s = 0.f;
    for (int i = 0; i < Ln; ++i) s += b2f(Hb[(size_t)(b * Ln + i) * Dn + d]);
    out[b * Dn + d] = s * (1.0f / (float)Ln);
}

// ---------------------------------------------------------------------------
extern "C" void kernel_launch(void* const* d_in, const int* in_sizes, int n_in,
                              void* d_out, int out_size, void* d_ws, size_t ws_size,
                              hipStream_t stream) {
    const float* x    = (const float*)d_in[0];
    const float* emb  = (const float*)d_in[1];
    const float* Wq   = (const float*)d_in[2];
    const float* bq   = (const float*)d_in[3];
    const float* Wk   = (const float*)d_in[4];
    const float* bk   = (const float*)d_in[5];
    const float* Wv   = (const float*)d_in[6];
    const float* bv   = (const float*)d_in[7];
    const float* Wo   = (const float*)d_in[8];
    const float* bo   = (const float*)d_in[9];
    const float* rk   = (const float*)d_in[10];
    const float* rb   = (const float*)d_in[11];
    const float* ln1g = (const float*)d_in[12];
    const float* ln1b = (const float*)d_in[13];
    const float* W1   = (const float*)d_in[14];
    const float* b1   = (const float*)d_in[15];
    const float* W2   = (const float*)d_in[16];
    const float* b2   = (const float*)d_in[17];
    const float* ln2g = (const float*)d_in[18];
    const float* ln2b = (const float*)d_in[19];

    float* out = (float*)d_out;
    float* avg = out + Bn * Dn;

    char* ws = (char*)d_ws;
    const size_t MB = 1024 * 1024;
    ushort* hb   = (ushort*)(ws);             // 2 MB   [4096][256]
    ushort* qkvb = (ushort*)(ws + 2 * MB);    // 6 MB   [4096][768]
    ushort* ctxb = (ushort*)(ws + 8 * MB);    // 2 MB
    ushort* t1   = (ushort*)(ws + 10 * MB);   // 2 MB
    ushort* ffb  = (ushort*)(ws + 12 * MB);   // 8 MB   [4096][1024]
    ushort* qkvT = (ushort*)(ws + 20 * MB);   // 1.5 MB [NL][768][256]
    ushort* WoT  = (ushort*)(ws + 22 * MB);   // 0.5 MB [NL][256][256]
    ushort* W1T  = (ushort*)(ws + 23 * MB);   // 2 MB   [NL][1024][256]
    ushort* W2T  = (ushort*)(ws + 25 * MB);   // 2 MB   [NL][256][1024]
    float*  bqkv = (float*)(ws + 27 * MB);            // 12 KB
    float*  bkT  = (float*)(ws + 27 * MB + 65536);    // 64 KB
    float*  bbT  = (float*)(ws + 27 * MB + 131072);   // 64 KB

    embed_k<<<NTOK, 256, 0, stream>>>(x, emb, hb);
    relbias_k<<<64, 256, 0, stream>>>(rk, rb, bkT, bbT);
    prep_bias<<<12, 256, 0, stream>>>(bq, bk, bv, bqkv);

    dim3 t88(8, 8, NLn);
    transpose_cvt<<<t88, 256, 0, stream>>>(Wq, qkvT + 0,      256, 256, 65536, 196608);
    transpose_cvt<<<t88, 256, 0, stream>>>(Wk, qkvT + 65536,  256, 256, 65536, 196608);
    transpose_cvt<<<t88, 256, 0, stream>>>(Wv, qkvT + 131072, 256, 256, 65536, 196608);
    transpose_cvt<<<t88, 256, 0, stream>>>(Wo, WoT,           256, 256, 65536, 65536);
    transpose_cvt<<<dim3(32, 8, NLn), 256, 0, stream>>>(W1, W1T, 256, 1024, 262144, 262144);
    transpose_cvt<<<dim3(8, 32, NLn), 256, 0, stream>>>(W2, W2T, 1024, 256, 262144, 262144);

    for (int l = 0; l < NLn; ++l) {
        gemm_mfma<<<dim3(12, 64), 256, 0, stream>>>(
            hb, qkvT + (size_t)l * 196608, bqkv + l * QKVW, qkvb, NTOK, QKVW, Dn, 0);
        attn_fused<<<dim3(Ln / ROWS, Hn, Bn), 256, 0, stream>>>(
            qkvb, bkT + l * Hn * Ln, bbT + l * Hn * Ln, ctxb, avg, (l == 0) ? 1 : 0);
        gemm_mfma<<<dim3(4, 64), 256, 0, stream>>>(
            ctxb, WoT + (size_t)l * 65536, bo + l * 256, t1, NTOK, Dn, Dn, 0);
        layernorm_k<<<NTOK / 4, 256, 0, stream>>>(
            t1, ln1g + l * 256, ln1b + l * 256, t1);
        gemm_mfma<<<dim3(16, 64), 256, 0, stream>>>(
            t1, W1T + (size_t)l * 262144, b1 + l * FFn, ffb, NTOK, FFn, Dn, 1);
        gemm_mfma<<<dim3(4, 64), 256, 0, stream>>>(
            ffb, W2T + (size_t)l * 262144, b2 + l * 256, hb, NTOK, Dn, FFn, 0);
        layernorm_k<<<NTOK / 4, 256, 0, stream>>>(
            hb, ln2g + l * 256, ln2b + l * 256, hb);
    }
    mean_rows_k<<<Bn, 256, 0, stream>>>(hb, out);
}

// Round 4
// 549.461 us; speedup vs baseline: 2.7427x; 2.6498x over previous
//
#include <hip/hip_runtime.h>
#include <hip/hip_bf16.h>
#include <math.h>

// Problem constants
#define Bn 4
#define Ln 1024
#define Vn 64
#define Dn 256
#define Hn 4
#define DKn 64
#define NLn 4
#define Mn 20
#define FFn 1024
#define NTOK (Bn * Ln)   // 4096
#define QKVW 768         // fused q|k|v width
#define LOG2E 1.4426950408889634f

typedef __attribute__((ext_vector_type(8))) short bf16x8;
typedef __attribute__((ext_vector_type(4))) float f32x4;

__device__ __forceinline__ ushort f2b(float f) {   // fp32 -> bf16 RNE
    uint u = __float_as_uint(f);
    u += 0x7fff + ((u >> 16) & 1);
    return (ushort)(u >> 16);
}
__device__ __forceinline__ float b2f(ushort u) {   // exact
    return __uint_as_float(((uint)u) << 16);
}

// ---------------------------------------------------------------------------
__global__ __launch_bounds__(256) void embed_k(const float* __restrict__ X,
                                               const float* __restrict__ E,
                                               ushort* __restrict__ Hb) {
    __shared__ float xs[Vn];
    int n = blockIdx.x, d = threadIdx.x;
    if (threadIdx.x < Vn) xs[threadIdx.x] = X[n * Vn + threadIdx.x];
    __syncthreads();
    float s = 0.f;
#pragma unroll
    for (int v = 0; v < Vn; ++v) s += xs[v] * E[v * Dn + d];
    Hb[(size_t)n * Dn + d] = f2b(s);
}

// ---------------------------------------------------------------------------
// bias tables, pre-scaled into exp2 domain:
//   bkT = rel_k * 0.125 * log2(e);  bbT = rel_b * log2(e)
__global__ __launch_bounds__(256) void relbias_k(const float* __restrict__ rk,
                                                 const float* __restrict__ rb,
                                                 float* __restrict__ bkT,
                                                 float* __restrict__ bbT) {
    int tid = blockIdx.x * 256 + threadIdx.x;   // < NL*H*1024
    int dist = tid & 1023;
    int hh = (tid >> 10) & 3;
    int l = tid >> 12;
    float dd = (float)dist;
    if (dist > Mn) dd = (float)Mn + log2f((float)(dist - Mn));
    if (dd > 2.0f * Mn) dd = 2.0f * Mn;
    int idx = (int)dd;
    bkT[tid] = rk[(l * (2 * Mn + 1) + idx) * Hn + hh] * 0.125f * LOG2E;
    bbT[tid] = rb[(l * (2 * Mn + 1) + idx) * Hn + hh] * LOG2E;
}

// ---------------------------------------------------------------------------
__global__ __launch_bounds__(256) void prep_bias(const float* __restrict__ bq,
                                                 const float* __restrict__ bk,
                                                 const float* __restrict__ bv,
                                                 float* __restrict__ bqkv) {
    int idx = blockIdx.x * 256 + threadIdx.x;   // < NL*768
    int l = idx / QKVW, r = idx - l * QKVW;
    float v;
    if (r < 256)      v = bq[l * 256 + r];
    else if (r < 512) v = bk[l * 256 + r - 256];
    else              v = bv[l * 256 + r - 512];
    bqkv[idx] = v;
}

// ---------------------------------------------------------------------------
// Weight transpose + fp32->bf16: dst[c][r] = src[r][c]; grid.z = layer.
__global__ __launch_bounds__(256) void transpose_cvt(
    const float* __restrict__ src, ushort* __restrict__ dst,
    int R, int C, int srcLS, int dstLS) {
    __shared__ float s[32][33];
    src += (size_t)blockIdx.z * srcLS;
    dst += (size_t)blockIdx.z * dstLS;
    int r0 = blockIdx.y * 32, c0 = blockIdx.x * 32;
    int tx = threadIdx.x & 31, ty = threadIdx.x >> 5;
#pragma unroll
    for (int ii = 0; ii < 4; ++ii)
        s[ty + 8 * ii][tx] = src[(size_t)(r0 + ty + 8 * ii) * C + c0 + tx];
    __syncthreads();
#pragma unroll
    for (int ii = 0; ii < 4; ++ii)
        dst[(size_t)(c0 + ty + 8 * ii) * R + r0 + tx] = f2b(s[tx][ty + 8 * ii]);
}

// ---------------------------------------------------------------------------
// V transpose per (b,h): Vt[bh][d][j] = qkvb[b*L+j][512 + h*64 + d]
__global__ __launch_bounds__(256) void transpose_v(const ushort* __restrict__ qkv,
                                                   ushort* __restrict__ Vt) {
    __shared__ ushort s[32][65];
    int j0 = blockIdx.x * 32;
    int bh = blockIdx.y;
    int b = bh >> 2, hh = bh & 3;
    int t = threadIdx.x;
#pragma unroll
    for (int ii = 0; ii < 8; ++ii) {
        int e = t + 256 * ii;          // 2048 = 32 j x 64 d
        int jr = e >> 6, dc = e & 63;
        s[jr][dc] = qkv[(size_t)(b * Ln + j0 + jr) * QKVW + 2 * Dn + hh * DKn + dc];
    }
    __syncthreads();
#pragma unroll
    for (int ii = 0; ii < 8; ++ii) {
        int e = t + 256 * ii;          // 2048 = 64 d x 32 j
        int dr = e >> 5, jc = e & 31;
        Vt[(size_t)(bh * DKn + dr) * Ln + j0 + jc] = s[jc][dr];
    }
}

// ---------------------------------------------------------------------------
// bf16 MFMA GEMM: C[m][n] = act(sum_k A[m][k]*Bt[n][k] + bias[n]), C bf16.
#define GST 40
__global__ __launch_bounds__(256) void gemm_mfma(
    const ushort* __restrict__ A, const ushort* __restrict__ Bt,
    const float* __restrict__ bias, ushort* __restrict__ C,
    int M, int N, int K, int act) {
    __shared__ __align__(16) ushort As[64 * GST];
    __shared__ __align__(16) ushort Bs[64 * GST];
    int t = threadIdx.x;
    int lane = t & 63, w = t >> 6;
    int wm = w >> 1, wn = w & 1;
    int l15 = lane & 15, lg = lane >> 4;
    int mBase = blockIdx.y * 64, nBase = blockIdx.x * 64;
    int lrow = t >> 2, lkc = (t & 3) * 8;
    const ushort* Ap = A + (size_t)(mBase + lrow) * K + lkc;
    const ushort* Bp = Bt + (size_t)(nBase + lrow) * K + lkc;
    f32x4 acc[2][2] = {};
    for (int k0 = 0; k0 < K; k0 += 32) {
        uint4 av = *(const uint4*)(Ap + k0);
        uint4 bv = *(const uint4*)(Bp + k0);
        __syncthreads();
        *(uint4*)&As[lrow * GST + lkc] = av;
        *(uint4*)&Bs[lrow * GST + lkc] = bv;
        __syncthreads();
        bf16x8 a0 = *(const bf16x8*)&As[(wm * 32 + l15) * GST + lg * 8];
        bf16x8 a1 = *(const bf16x8*)&As[(wm * 32 + 16 + l15) * GST + lg * 8];
        bf16x8 b0 = *(const bf16x8*)&Bs[(wn * 32 + l15) * GST + lg * 8];
        bf16x8 b1 = *(const bf16x8*)&Bs[(wn * 32 + 16 + l15) * GST + lg * 8];
        acc[0][0] = __builtin_amdgcn_mfma_f32_16x16x32_bf16(a0, b0, acc[0][0], 0, 0, 0);
        acc[0][1] = __builtin_amdgcn_mfma_f32_16x16x32_bf16(a0, b1, acc[0][1], 0, 0, 0);
        acc[1][0] = __builtin_amdgcn_mfma_f32_16x16x32_bf16(a1, b0, acc[1][0], 0, 0, 0);
        acc[1][1] = __builtin_amdgcn_mfma_f32_16x16x32_bf16(a1, b1, acc[1][1], 0, 0, 0);
    }
#pragma unroll
    for (int ni = 0; ni < 2; ++ni) {
        int col = nBase + wn * 32 + ni * 16 + l15;
        float bc = bias[col];
#pragma unroll
        for (int mi = 0; mi < 2; ++mi) {
            int rb = mBase + wm * 32 + mi * 16 + lg * 4;
#pragma unroll
            for (int j = 0; j < 4; ++j) {
                float v = acc[mi][ni][j] + bc;
                if (act) v = v * 0.5f * (1.0f + erff(v * 0.7071067811865475f));
                C[(size_t)(rb + j) * N + col] = f2b(v);
            }
        }
    }
}

// ---------------------------------------------------------------------------
// MFMA flash-style attention with per-head rel bias + avg_attn output.
// Grid: 512 blocks (XCD-swizzled). 4 waves: wm = q-row 16-block, wn = col half.
// Softmax (m,l): in-wave shuffle merge over l15, then cross-wn LDS merge.
// PV in bf16 hi/lo split for ~fp32 P precision.
__global__ __launch_bounds__(256) void attn_fused(
    const ushort* __restrict__ qkv, const ushort* __restrict__ Vt,
    const float* __restrict__ bkTab, const float* __restrict__ bbTab,
    ushort* __restrict__ ctx, float* __restrict__ avg, int first) {
    __shared__ float bk_l[Ln];
    __shared__ float bb_l[Ln];
    __shared__ __align__(16) ushort Ps[32 * 64];   // XOR-swizzled P tile (hi)
    __shared__ __align__(16) ushort Pl[32 * 64];   // XOR-swizzled P tile (lo)
    __shared__ float mml[2][32];
    __shared__ float lml[2][32];

    int t = threadIdx.x;
    int lane = t & 63, w = t >> 6;
    int wm = w >> 1, wn = w & 1;
    int l15 = lane & 15, lg = lane >> 4;

    int bid = blockIdx.x;
    int xcd = bid & 7, sub = bid >> 3;
    int bh = xcd * 2 + (sub >> 5);
    int q = sub & 31;
    int b = bh >> 2, hh = bh & 3;
    int i0 = q * 32;

#pragma unroll
    for (int ii = 0; ii < 4; ++ii) {
        bk_l[t + 256 * ii] = bkTab[hh * Ln + t + 256 * ii];
        bb_l[t + 256 * ii] = bbTab[hh * Ln + t + 256 * ii];
    }
    __syncthreads();

    // Q fragments (A-operand): row = i0 + wm*16 + l15, k = kc*32 + lg*8
    bf16x8 qa[2];
    {
        const ushort* qp = qkv + (size_t)(b * Ln + i0 + wm * 16 + l15) * QKVW + hh * DKn;
        qa[0] = *(const bf16x8*)(qp + lg * 8);
        qa[1] = *(const bf16x8*)(qp + 32 + lg * 8);
    }

    int irow[4];
    float m[4], lsum[4];
#pragma unroll
    for (int r = 0; r < 4; ++r) {
        irow[r] = i0 + wm * 16 + lg * 4 + r;
        m[r] = -1e30f;
        lsum[r] = 0.f;
    }

    const ushort* kbase = qkv + (size_t)(b * Ln) * QKVW + Dn + hh * DKn;

    // ---------------- pass 1: running (m, l) in exp2 domain -----------------
    for (int c = 0; c < 16; ++c) {
        f32x4 acc[2] = {};
#pragma unroll
        for (int ni = 0; ni < 2; ++ni) {
            const ushort* kp = kbase + (size_t)(c * 64 + wn * 32 + ni * 16 + l15) * QKVW;
            bf16x8 k0 = *(const bf16x8*)(kp + lg * 8);
            bf16x8 k1 = *(const bf16x8*)(kp + 32 + lg * 8);
            acc[ni] = __builtin_amdgcn_mfma_f32_16x16x32_bf16(qa[0], k0, acc[ni], 0, 0, 0);
            acc[ni] = __builtin_amdgcn_mfma_f32_16x16x32_bf16(qa[1], k1, acc[ni], 0, 0, 0);
        }
#pragma unroll
        for (int r = 0; r < 4; ++r) {
            int i = irow[r];
            int j0c = c * 64 + wn * 32 + l15;
            int d0 = (i > j0c) ? (i - j0c) : (j0c - i);
            float s0 = acc[0][r] * bk_l[d0] + bb_l[d0];
            int j1c = j0c + 16;
            int d1 = (i > j1c) ? (i - j1c) : (j1c - i);
            float s1 = acc[1][r] * bk_l[d1] + bb_l[d1];
            float cm = fmaxf(s0, s1);
            float nm = fmaxf(m[r], cm);
            lsum[r] = lsum[r] * exp2f(m[r] - nm) + exp2f(s0 - nm) + exp2f(s1 - nm);
            m[r] = nm;
        }
    }
    // in-wave merge over the 16 col-lanes (masks 1,2,4,8)
#pragma unroll
    for (int mask = 1; mask < 16; mask <<= 1) {
#pragma unroll
        for (int r = 0; r < 4; ++r) {
            float om = __shfl_xor(m[r], mask, 64);
            float ol = __shfl_xor(lsum[r], mask, 64);
            float nm = fmaxf(m[r], om);
            lsum[r] = lsum[r] * exp2f(m[r] - nm) + ol * exp2f(om - nm);
            m[r] = nm;
        }
    }
    // cross-wn merge via LDS: each wave publishes its half-row (m,l)
    if (l15 == 0) {
#pragma unroll
        for (int r = 0; r < 4; ++r) {
            mml[wn][wm * 16 + lg * 4 + r] = m[r];
            lml[wn][wm * 16 + lg * 4 + r] = lsum[r];
        }
    }
    __syncthreads();
#pragma unroll
    for (int r = 0; r < 4; ++r) {
        int qr = wm * 16 + lg * 4 + r;
        float om = mml[wn ^ 1][qr];
        float ol = lml[wn ^ 1][qr];
        float nm = fmaxf(m[r], om);
        lsum[r] = lsum[r] * exp2f(m[r] - nm) + ol * exp2f(om - nm);
        m[r] = nm;
    }
    float invl[4];
#pragma unroll
    for (int r = 0; r < 4; ++r) invl[r] = 1.0f / lsum[r];

    const ushort* vtb = Vt + (size_t)bh * DKn * Ln;
    f32x4 acco[2] = {};

    // ---------------- pass 2: recompute S, write avg, PV ---------------------
    for (int c = 0; c < 16; ++c) {
        f32x4 acc[2] = {};
#pragma unroll
        for (int ni = 0; ni < 2; ++ni) {
            const ushort* kp = kbase + (size_t)(c * 64 + wn * 32 + ni * 16 + l15) * QKVW;
            bf16x8 k0 = *(const bf16x8*)(kp + lg * 8);
            bf16x8 k1 = *(const bf16x8*)(kp + 32 + lg * 8);
            acc[ni] = __builtin_amdgcn_mfma_f32_16x16x32_bf16(qa[0], k0, acc[ni], 0, 0, 0);
            acc[ni] = __builtin_amdgcn_mfma_f32_16x16x32_bf16(qa[1], k1, acc[ni], 0, 0, 0);
        }
        __syncthreads();   // previous chunk's Ps/Pl reads complete
#pragma unroll
        for (int r = 0; r < 4; ++r) {
            int i = irow[r];
            int iloc = wm * 16 + lg * 4 + r;
#pragma unroll
            for (int ni = 0; ni < 2; ++ni) {
                int jloc = wn * 32 + ni * 16 + l15;
                int j = c * 64 + jloc;
                int dist = (i > j) ? (i - j) : (j - i);
                float s = acc[ni][r] * bk_l[dist] + bb_l[dist];
                float p = exp2f(s - m[r]) * invl[r];
                ushort ph = f2b(p);
                ushort plo = f2b(p - b2f(ph));
                int byte = iloc * 128 + ((jloc * 2) ^ ((iloc & 7) << 4));
                *(ushort*)((char*)Ps + byte) = ph;
                *(ushort*)((char*)Pl + byte) = plo;
                size_t oidx = ((size_t)bh * Ln + i) * Ln + j;
                if (first) avg[oidx] = 0.25f * p;
                else       avg[oidx] += 0.25f * p;
            }
        }
        __syncthreads();   // Ps/Pl ready
        // PV: O^T = V^T * (P_hi + P_lo)^T
        bf16x8 pbh[2], pbl[2];
        {
            int prow = wm * 16 + l15;
#pragma unroll
            for (int kc = 0; kc < 2; ++kc) {
                int byte = prow * 128 + (((kc * 4 + lg) * 16) ^ ((prow & 7) << 4));
                pbh[kc] = *(const bf16x8*)((char*)Ps + byte);
                pbl[kc] = *(const bf16x8*)((char*)Pl + byte);
            }
        }
#pragma unroll
        for (int di = 0; di < 2; ++di) {
            const ushort* vp = vtb + (size_t)(wn * 32 + di * 16 + l15) * Ln + c * 64;
            bf16x8 v0 = *(const bf16x8*)(vp + lg * 8);
            bf16x8 v1 = *(const bf16x8*)(vp + 32 + lg * 8);
            acco[di] = __builtin_amdgcn_mfma_f32_16x16x32_bf16(v0, pbh[0], acco[di], 0, 0, 0);
            acco[di] = __builtin_amdgcn_mfma_f32_16x16x32_bf16(v1, pbh[1], acco[di], 0, 0, 0);
            acco[di] = __builtin_amdgcn_mfma_f32_16x16x32_bf16(v0, pbl[0], acco[di], 0, 0, 0);
            acco[di] = __builtin_amdgcn_mfma_f32_16x16x32_bf16(v1, pbl[1], acco[di], 0, 0, 0);
        }
    }

    // write O: lane holds O[i][d], i = i0+wm*16+l15, d = wn*32+di*16+lg*4+{0..3}
    {
        int i = i0 + wm * 16 + l15;
#pragma unroll
        for (int di = 0; di < 2; ++di) {
            uint lo = (uint)f2b(acco[di][0]) | ((uint)f2b(acco[di][1]) << 16);
            uint hi = (uint)f2b(acco[di][2]) | ((uint)f2b(acco[di][3]) << 16);
            uint2 pk = make_uint2(lo, hi);
            *(uint2*)&ctx[(size_t)(b * Ln + i) * Dn + hh * DKn + wn * 32 + di * 16 + lg * 4] = pk;
        }
    }
}

// ---------------------------------------------------------------------------
__global__ __launch_bounds__(256) void layernorm_k(const ushort* __restrict__ X,
                                                   const float* __restrict__ g,
                                                   const float* __restrict__ bta,
                                                   ushort* __restrict__ Y) {
    int w = threadIdx.x >> 6, lane = threadIdx.x & 63;
    int row = blockIdx.x * 4 + w;
    const ushort* xr = X + (size_t)row * Dn;
    float x[4];
#pragma unroll
    for (int ii = 0; ii < 4; ++ii) x[ii] = b2f(xr[lane + 64 * ii]);
    float s = x[0] + x[1] + x[2] + x[3];
#pragma unroll
    for (int m = 1; m < 64; m <<= 1) s += __shfl_xor(s, m, 64);
    float mu = s * (1.0f / 256.0f);
    float vs = 0.f;
#pragma unroll
    for (int ii = 0; ii < 4; ++ii) {
        float d = x[ii] - mu;
        vs += d * d;
    }
#pragma unroll
    for (int m = 1; m < 64; m <<= 1) vs += __shfl_xor(vs, m, 64);
    float rs = rsqrtf(vs * (1.0f / 256.0f) + 1e-5f);
#pragma unroll
    for (int ii = 0; ii < 4; ++ii) {
        int d = lane + 64 * ii;
        Y[(size_t)row * Dn + d] = f2b((x[ii] - mu) * rs * g[d] + bta[d]);
    }
}

// ---------------------------------------------------------------------------
__global__ __launch_bounds__(256) void mean_part_k(const ushort* __restrict__ Hb,
                                                   float* __restrict__ part) {
    int blk = blockIdx.x;            // 64 = 4 b x 16 groups
    int b = blk >> 4, g = blk & 15;
    int d = threadIdx.x;
    float s = 0.f;
#pragma unroll
    for (int r = 0; r < 64; ++r)
        s += b2f(Hb[(size_t)(b * Ln + g * 64 + r) * Dn + d]);
    part[(size_t)blk * Dn + d] = s;
}
__global__ __launch_bounds__(256) void mean_final_k(const float* __restrict__ part,
                                                    float* __restrict__ out) {
    int b = blockIdx.x, d = threadIdx.x;
    float s = 0.f;
#pragma unroll
    for (int g = 0; g < 16; ++g) s += part[(size_t)(b * 16 + g) * Dn + d];
    out[b * Dn + d] = s * (1.0f / (float)Ln);
}

// ---------------------------------------------------------------------------
extern "C" void kernel_launch(void* const* d_in, const int* in_sizes, int n_in,
                              void* d_out, int out_size, void* d_ws, size_t ws_size,
                              hipStream_t stream) {
    const float* x    = (const float*)d_in[0];
    const float* emb  = (const float*)d_in[1];
    const float* Wq   = (const float*)d_in[2];
    const float* bq   = (const float*)d_in[3];
    const float* Wk   = (const float*)d_in[4];
    const float* bk   = (const float*)d_in[5];
    const float* Wv   = (const float*)d_in[6];
    const float* bv   = (const float*)d_in[7];
    const float* Wo   = (const float*)d_in[8];
    const float* bo   = (const float*)d_in[9];
    const float* rk   = (const float*)d_in[10];
    const float* rb   = (const float*)d_in[11];
    const float* ln1g = (const float*)d_in[12];
    const float* ln1b = (const float*)d_in[13];
    const float* W1   = (const float*)d_in[14];
    const float* b1   = (const float*)d_in[15];
    const float* W2   = (const float*)d_in[16];
    const float* b2   = (const float*)d_in[17];
    const float* ln2g = (const float*)d_in[18];
    const float* ln2b = (const float*)d_in[19];

    float* out = (float*)d_out;
    float* avg = out + Bn * Dn;

    char* ws = (char*)d_ws;
    const size_t MB = 1024 * 1024;
    ushort* hb   = (ushort*)(ws);             // 2 MB
    ushort* qkvb = (ushort*)(ws + 2 * MB);    // 6 MB
    ushort* ctxb = (ushort*)(ws + 8 * MB);    // 2 MB
    ushort* t1   = (ushort*)(ws + 10 * MB);   // 2 MB
    ushort* ffb  = (ushort*)(ws + 12 * MB);   // 8 MB
    ushort* qkvT = (ushort*)(ws + 20 * MB);   // 1.5 MB
    ushort* WoT  = (ushort*)(ws + 22 * MB);   // 0.5 MB
    ushort* W1T  = (ushort*)(ws + 23 * MB);   // 2 MB
    ushort* W2T  = (ushort*)(ws + 25 * MB);   // 2 MB
    float*  bqkv = (float*)(ws + 27 * MB);
    float*  bkT  = (float*)(ws + 27 * MB + 65536);
    float*  bbT  = (float*)(ws + 27 * MB + 131072);
    ushort* Vt   = (ushort*)(ws + 30 * MB);   // 2 MB
    float*  mpart= (float*)(ws + 33 * MB);    // 64 KB

    embed_k<<<NTOK, 256, 0, stream>>>(x, emb, hb);
    relbias_k<<<64, 256, 0, stream>>>(rk, rb, bkT, bbT);
    prep_bias<<<12, 256, 0, stream>>>(bq, bk, bv, bqkv);

    dim3 t88(8, 8, NLn);
    transpose_cvt<<<t88, 256, 0, stream>>>(Wq, qkvT + 0,      256, 256, 65536, 196608);
    transpose_cvt<<<t88, 256, 0, stream>>>(Wk, qkvT + 65536,  256, 256, 65536, 196608);
    transpose_cvt<<<t88, 256, 0, stream>>>(Wv, qkvT + 131072, 256, 256, 65536, 196608);
    transpose_cvt<<<t88, 256, 0, stream>>>(Wo, WoT,           256, 256, 65536, 65536);
    transpose_cvt<<<dim3(32, 8, NLn), 256, 0, stream>>>(W1, W1T, 256, 1024, 262144, 262144);
    transpose_cvt<<<dim3(8, 32, NLn), 256, 0, stream>>>(W2, W2T, 1024, 256, 262144, 262144);

    for (int l = 0; l < NLn; ++l) {
        gemm_mfma<<<dim3(12, 64), 256, 0, stream>>>(
            hb, qkvT + (size_t)l * 196608, bqkv + l * QKVW, qkvb, NTOK, QKVW, Dn, 0);
        transpose_v<<<dim3(32, 16), 256, 0, stream>>>(qkvb, Vt);
        attn_fused<<<512, 256, 0, stream>>>(
            qkvb, Vt, bkT + l * Hn * Ln, bbT + l * Hn * Ln, ctxb, avg, (l == 0) ? 1 : 0);
        gemm_mfma<<<dim3(4, 64), 256, 0, stream>>>(
            ctxb, WoT + (size_t)l * 65536, bo + l * 256, t1, NTOK, Dn, Dn, 0);
        layernorm_k<<<NTOK / 4, 256, 0, stream>>>(
            t1, ln1g + l * 256, ln1b + l * 256, t1);
        gemm_mfma<<<dim3(16, 64), 256, 0, stream>>>(
            t1, W1T + (size_t)l * 262144, b1 + l * FFn, ffb, NTOK, FFn, Dn, 1);
        gemm_mfma<<<dim3(4, 64), 256, 0, stream>>>(
            ffb, W2T + (size_t)l * 262144, b2 + l * 256, hb, NTOK, Dn, FFn, 0);
        layernorm_k<<<NTOK / 4, 256, 0, stream>>>(
            hb, ln2g + l * 256, ln2b + l * 256, hb);
    }
    mean_part_k<<<64, 256, 0, stream>>>(hb, mpart);
    mean_final_k<<<Bn, 256, 0, stream>>>(mpart, out);
}

// Round 5
// 519.501 us; speedup vs baseline: 2.9009x; 1.0577x over previous
//
#include <hip/hip_runtime.h>
#include <hip/hip_bf16.h>
#include <math.h>

// Problem constants
#define Bn 4
#define Ln 1024
#define Vn 64
#define Dn 256
#define Hn 4
#define DKn 64
#define NLn 4
#define Mn 20
#define FFn 1024
#define NTOK (Bn * Ln)   // 4096
#define QKVW 768         // fused q|k|v width
#define LOG2E 1.4426950408889634f

typedef __attribute__((ext_vector_type(8))) short bf16x8;
typedef __attribute__((ext_vector_type(4))) float f32x4;

__device__ __forceinline__ ushort f2b(float f) {   // fp32 -> bf16 RNE
    uint u = __float_as_uint(f);
    u += 0x7fff + ((u >> 16) & 1);
    return (ushort)(u >> 16);
}
__device__ __forceinline__ float b2f(ushort u) {   // exact
    return __uint_as_float(((uint)u) << 16);
}

// ---------------------------------------------------------------------------
__global__ __launch_bounds__(256) void embed_k(const float* __restrict__ X,
                                               const float* __restrict__ E,
                                               ushort* __restrict__ Hb) {
    __shared__ float xs[Vn];
    int n = blockIdx.x, d = threadIdx.x;
    if (threadIdx.x < Vn) xs[threadIdx.x] = X[n * Vn + threadIdx.x];
    __syncthreads();
    float s = 0.f;
#pragma unroll
    for (int v = 0; v < Vn; ++v) s += xs[v] * E[v * Dn + d];
    Hb[(size_t)n * Dn + d] = f2b(s);
}

// ---------------------------------------------------------------------------
// bias tables, pre-scaled into exp2 domain:
//   bkT = rel_k * 0.125 * log2(e);  bbT = rel_b * log2(e)
__global__ __launch_bounds__(256) void relbias_k(const float* __restrict__ rk,
                                                 const float* __restrict__ rb,
                                                 float* __restrict__ bkT,
                                                 float* __restrict__ bbT) {
    int tid = blockIdx.x * 256 + threadIdx.x;   // < NL*H*1024
    int dist = tid & 1023;
    int hh = (tid >> 10) & 3;
    int l = tid >> 12;
    float dd = (float)dist;
    if (dist > Mn) dd = (float)Mn + log2f((float)(dist - Mn));
    if (dd > 2.0f * Mn) dd = 2.0f * Mn;
    int idx = (int)dd;
    bkT[tid] = rk[(l * (2 * Mn + 1) + idx) * Hn + hh] * 0.125f * LOG2E;
    bbT[tid] = rb[(l * (2 * Mn + 1) + idx) * Hn + hh] * LOG2E;
}

// ---------------------------------------------------------------------------
__global__ __launch_bounds__(256) void prep_bias(const float* __restrict__ bq,
                                                 const float* __restrict__ bk,
                                                 const float* __restrict__ bv,
                                                 float* __restrict__ bqkv) {
    int idx = blockIdx.x * 256 + threadIdx.x;   // < NL*768
    int l = idx / QKVW, r = idx - l * QKVW;
    float v;
    if (r < 256)      v = bq[l * 256 + r];
    else if (r < 512) v = bk[l * 256 + r - 256];
    else              v = bv[l * 256 + r - 512];
    bqkv[idx] = v;
}

// ---------------------------------------------------------------------------
// Weight transpose + fp32->bf16: dst[c][r] = src[r][c]; grid.z = layer.
__global__ __launch_bounds__(256) void transpose_cvt(
    const float* __restrict__ src, ushort* __restrict__ dst,
    int R, int C, int srcLS, int dstLS) {
    __shared__ float s[32][33];
    src += (size_t)blockIdx.z * srcLS;
    dst += (size_t)blockIdx.z * dstLS;
    int r0 = blockIdx.y * 32, c0 = blockIdx.x * 32;
    int tx = threadIdx.x & 31, ty = threadIdx.x >> 5;
#pragma unroll
    for (int ii = 0; ii < 4; ++ii)
        s[ty + 8 * ii][tx] = src[(size_t)(r0 + ty + 8 * ii) * C + c0 + tx];
    __syncthreads();
#pragma unroll
    for (int ii = 0; ii < 4; ++ii)
        dst[(size_t)(c0 + ty + 8 * ii) * R + r0 + tx] = f2b(s[tx][ty + 8 * ii]);
}

// ---------------------------------------------------------------------------
// V transpose per (b,h): Vt[bh][d][j] = qkvb[b*L+j][512 + h*64 + d]
__global__ __launch_bounds__(256) void transpose_v(const ushort* __restrict__ qkv,
                                                   ushort* __restrict__ Vt) {
    __shared__ ushort s[32][65];
    int j0 = blockIdx.x * 32;
    int bh = blockIdx.y;
    int b = bh >> 2, hh = bh & 3;
    int t = threadIdx.x;
#pragma unroll
    for (int ii = 0; ii < 8; ++ii) {
        int e = t + 256 * ii;          // 2048 = 32 j x 64 d
        int jr = e >> 6, dc = e & 63;
        s[jr][dc] = qkv[(size_t)(b * Ln + j0 + jr) * QKVW + 2 * Dn + hh * DKn + dc];
    }
    __syncthreads();
#pragma unroll
    for (int ii = 0; ii < 8; ++ii) {
        int e = t + 256 * ii;          // 2048 = 64 d x 32 j
        int dr = e >> 5, jc = e & 31;
        Vt[(size_t)(bh * DKn + dr) * Ln + j0 + jc] = s[jc][dr];
    }
}

// ---------------------------------------------------------------------------
// bf16 MFMA GEMM: C[m][n] = act(sum_k A[m][k]*Bt[n][k] + bias[n]), C bf16.
#define GST 40
__global__ __launch_bounds__(256) void gemm_mfma(
    const ushort* __restrict__ A, const ushort* __restrict__ Bt,
    const float* __restrict__ bias, ushort* __restrict__ C,
    int M, int N, int K, int act) {
    __shared__ __align__(16) ushort As[64 * GST];
    __shared__ __align__(16) ushort Bs[64 * GST];
    int t = threadIdx.x;
    int lane = t & 63, w = t >> 6;
    int wm = w >> 1, wn = w & 1;
    int l15 = lane & 15, lg = lane >> 4;
    int mBase = blockIdx.y * 64, nBase = blockIdx.x * 64;
    int lrow = t >> 2, lkc = (t & 3) * 8;
    const ushort* Ap = A + (size_t)(mBase + lrow) * K + lkc;
    const ushort* Bp = Bt + (size_t)(nBase + lrow) * K + lkc;
    f32x4 acc[2][2] = {};
    for (int k0 = 0; k0 < K; k0 += 32) {
        uint4 av = *(const uint4*)(Ap + k0);
        uint4 bv = *(const uint4*)(Bp + k0);
        __syncthreads();
        *(uint4*)&As[lrow * GST + lkc] = av;
        *(uint4*)&Bs[lrow * GST + lkc] = bv;
        __syncthreads();
        bf16x8 a0 = *(const bf16x8*)&As[(wm * 32 + l15) * GST + lg * 8];
        bf16x8 a1 = *(const bf16x8*)&As[(wm * 32 + 16 + l15) * GST + lg * 8];
        bf16x8 b0 = *(const bf16x8*)&Bs[(wn * 32 + l15) * GST + lg * 8];
        bf16x8 b1 = *(const bf16x8*)&Bs[(wn * 32 + 16 + l15) * GST + lg * 8];
        acc[0][0] = __builtin_amdgcn_mfma_f32_16x16x32_bf16(a0, b0, acc[0][0], 0, 0, 0);
        acc[0][1] = __builtin_amdgcn_mfma_f32_16x16x32_bf16(a0, b1, acc[0][1], 0, 0, 0);
        acc[1][0] = __builtin_amdgcn_mfma_f32_16x16x32_bf16(a1, b0, acc[1][0], 0, 0, 0);
        acc[1][1] = __builtin_amdgcn_mfma_f32_16x16x32_bf16(a1, b1, acc[1][1], 0, 0, 0);
    }
#pragma unroll
    for (int ni = 0; ni < 2; ++ni) {
        int col = nBase + wn * 32 + ni * 16 + l15;
        float bc = bias[col];
#pragma unroll
        for (int mi = 0; mi < 2; ++mi) {
            int rb = mBase + wm * 32 + mi * 16 + lg * 4;
#pragma unroll
            for (int j = 0; j < 4; ++j) {
                float v = acc[mi][ni][j] + bc;
                if (act) v = v * 0.5f * (1.0f + erff(v * 0.7071067811865475f));
                C[(size_t)(rb + j) * N + col] = f2b(v);
            }
        }
    }
}

// ---------------------------------------------------------------------------
// MFMA flash attention, single QK pass, scores in registers.
// Grid: 1024 blocks (XCD-swizzled; 16 q-rows each). 4 waves split the 64-col
// chunk 4-way. Softmax merge: 4 shuffles (l15) + LDS merge across 4 waves.
// PV: O^T = V^T * P^T, P in bf16 hi/lo split, XOR-swizzled 16x64 LDS tiles.
__global__ __launch_bounds__(256) void attn_fused(
    const ushort* __restrict__ qkv, const ushort* __restrict__ Vt,
    const float* __restrict__ bkTab, const float* __restrict__ bbTab,
    ushort* __restrict__ ctx, float* __restrict__ avg, int first) {
    __shared__ float bk_l[Ln];
    __shared__ float bb_l[Ln];
    __shared__ __align__(16) ushort Ps[16 * 64];   // P hi, XOR-swizzled
    __shared__ __align__(16) ushort Pl[16 * 64];   // P lo
    __shared__ float mm[4][16];
    __shared__ float ll[4][16];

    int t = threadIdx.x;
    int lane = t & 63, wn = t >> 6;       // wave = column quarter
    int l15 = lane & 15, lg = lane >> 4;

    int bid = blockIdx.x;
    int xcd = bid & 7, sub = bid >> 3;    // sub in [0,128)
    int bh = xcd * 2 + (sub >> 6);
    int q = sub & 63;
    int b = bh >> 2, hh = bh & 3;
    int i0 = q * 16;

#pragma unroll
    for (int ii = 0; ii < 4; ++ii) {
        bk_l[t + 256 * ii] = bkTab[hh * Ln + t + 256 * ii];
        bb_l[t + 256 * ii] = bbTab[hh * Ln + t + 256 * ii];
    }
    __syncthreads();

    // Q fragment (A-operand): row = i0 + l15, k = lg*8 (+32)
    bf16x8 qa0, qa1;
    {
        const ushort* qp = qkv + (size_t)(b * Ln + i0 + l15) * QKVW + hh * DKn;
        qa0 = *(const bf16x8*)(qp + lg * 8);
        qa1 = *(const bf16x8*)(qp + 32 + lg * 8);
    }

    const ushort* kbase = qkv + (size_t)(b * Ln) * QKVW + Dn + hh * DKn;

    // ---- QK pass: S kept in registers (fully unrolled -> static idx) -------
    f32x4 sv[16];
    float m[4] = {-1e30f, -1e30f, -1e30f, -1e30f};
#pragma unroll
    for (int c = 0; c < 16; ++c) {
        const ushort* kp = kbase + (size_t)(c * 64 + wn * 16 + l15) * QKVW;
        bf16x8 k0 = *(const bf16x8*)(kp + lg * 8);
        bf16x8 k1 = *(const bf16x8*)(kp + 32 + lg * 8);
        f32x4 acc = {};
        acc = __builtin_amdgcn_mfma_f32_16x16x32_bf16(qa0, k0, acc, 0, 0, 0);
        acc = __builtin_amdgcn_mfma_f32_16x16x32_bf16(qa1, k1, acc, 0, 0, 0);
        int j = c * 64 + wn * 16 + l15;
#pragma unroll
        for (int r = 0; r < 4; ++r) {
            int i = i0 + lg * 4 + r;
            int dist = (i > j) ? (i - j) : (j - i);
            float s = acc[r] * bk_l[dist] + bb_l[dist];
            sv[c][r] = s;
            m[r] = fmaxf(m[r], s);
        }
    }
    // merge max over the 16 l15-lanes
#pragma unroll
    for (int mask = 1; mask < 16; mask <<= 1)
#pragma unroll
        for (int r = 0; r < 4; ++r) m[r] = fmaxf(m[r], __shfl_xor(m[r], mask, 64));
    // merge max across the 4 waves
    if (l15 == 0)
#pragma unroll
        for (int r = 0; r < 4; ++r) mm[wn][lg * 4 + r] = m[r];
    __syncthreads();
#pragma unroll
    for (int r = 0; r < 4; ++r) {
        int row = lg * 4 + r;
        m[r] = fmaxf(fmaxf(mm[0][row], mm[1][row]), fmaxf(mm[2][row], mm[3][row]));
    }
    // p_unnorm = exp2(s - m); accumulate row sums
    float lsum[4] = {0.f, 0.f, 0.f, 0.f};
#pragma unroll
    for (int c = 0; c < 16; ++c)
#pragma unroll
        for (int r = 0; r < 4; ++r) {
            float p = exp2f(sv[c][r] - m[r]);
            sv[c][r] = p;
            lsum[r] += p;
        }
#pragma unroll
    for (int mask = 1; mask < 16; mask <<= 1)
#pragma unroll
        for (int r = 0; r < 4; ++r) lsum[r] += __shfl_xor(lsum[r], mask, 64);
    if (l15 == 0)
#pragma unroll
        for (int r = 0; r < 4; ++r) ll[wn][lg * 4 + r] = lsum[r];
    __syncthreads();
    float invl[4];
#pragma unroll
    for (int r = 0; r < 4; ++r) {
        int row = lg * 4 + r;
        invl[r] = 1.0f / (ll[0][row] + ll[1][row] + ll[2][row] + ll[3][row]);
    }

    // ---- avg write (barrier-free; normalize sv in place) -------------------
#pragma unroll
    for (int c = 0; c < 16; ++c) {
        int j = c * 64 + wn * 16 + l15;
#pragma unroll
        for (int r = 0; r < 4; ++r) {
            float p = sv[c][r] * invl[r];
            sv[c][r] = p;
            size_t oidx = ((size_t)bh * Ln + i0 + lg * 4 + r) * Ln + j;
            if (first) avg[oidx] = 0.25f * p;
            else       avg[oidx] += 0.25f * p;
        }
    }

    // ---- PV: O^T = V^T * (P_hi + P_lo)^T ------------------------------------
    const ushort* vtb = Vt + ((size_t)bh * DKn + wn * 16 + l15) * Ln;
    f32x4 acco = {};
#pragma unroll
    for (int c = 0; c < 16; ++c) {
#pragma unroll
        for (int r = 0; r < 4; ++r) {
            int row = lg * 4 + r;
            int byte = row * 128 + (((wn * 16 + l15) * 2) ^ ((row & 7) << 4));
            float p = sv[c][r];
            ushort ph = f2b(p);
            *(ushort*)((char*)Ps + byte) = ph;
            *(ushort*)((char*)Pl + byte) = f2b(p - b2f(ph));
        }
        __syncthreads();   // P tile ready
        bf16x8 v0 = *(const bf16x8*)(vtb + c * 64 + lg * 8);
        bf16x8 v1 = *(const bf16x8*)(vtb + c * 64 + 32 + lg * 8);
        bf16x8 pbh[2], pbl[2];
#pragma unroll
        for (int kc = 0; kc < 2; ++kc) {
            int byte = l15 * 128 + (((kc * 4 + lg) * 16) ^ ((l15 & 7) << 4));
            pbh[kc] = *(const bf16x8*)((char*)Ps + byte);
            pbl[kc] = *(const bf16x8*)((char*)Pl + byte);
        }
        acco = __builtin_amdgcn_mfma_f32_16x16x32_bf16(v0, pbh[0], acco, 0, 0, 0);
        acco = __builtin_amdgcn_mfma_f32_16x16x32_bf16(v1, pbh[1], acco, 0, 0, 0);
        acco = __builtin_amdgcn_mfma_f32_16x16x32_bf16(v0, pbl[0], acco, 0, 0, 0);
        acco = __builtin_amdgcn_mfma_f32_16x16x32_bf16(v1, pbl[1], acco, 0, 0, 0);
        __syncthreads();   // reads done before next chunk's writes
    }

    // O^T[d = wn*16+lg*4+r][qrow = l15] -> ctx[i0+l15][hh*64 + d]
    {
        uint lo = (uint)f2b(acco[0]) | ((uint)f2b(acco[1]) << 16);
        uint hi = (uint)f2b(acco[2]) | ((uint)f2b(acco[3]) << 16);
        uint2 pk = make_uint2(lo, hi);
        *(uint2*)&ctx[(size_t)(b * Ln + i0 + l15) * Dn + hh * DKn + wn * 16 + lg * 4] = pk;
    }
}

// ---------------------------------------------------------------------------
__global__ __launch_bounds__(256) void layernorm_k(const ushort* __restrict__ X,
                                                   const float* __restrict__ g,
                                                   const float* __restrict__ bta,
                                                   ushort* __restrict__ Y) {
    int w = threadIdx.x >> 6, lane = threadIdx.x & 63;
    int row = blockIdx.x * 4 + w;
    const ushort* xr = X + (size_t)row * Dn;
    float x[4];
#pragma unroll
    for (int ii = 0; ii < 4; ++ii) x[ii] = b2f(xr[lane + 64 * ii]);
    float s = x[0] + x[1] + x[2] + x[3];
#pragma unroll
    for (int m = 1; m < 64; m <<= 1) s += __shfl_xor(s, m, 64);
    float mu = s * (1.0f / 256.0f);
    float vs = 0.f;
#pragma unroll
    for (int ii = 0; ii < 4; ++ii) {
        float d = x[ii] - mu;
        vs += d * d;
    }
#pragma unroll
    for (int m = 1; m < 64; m <<= 1) vs += __shfl_xor(vs, m, 64);
    float rs = rsqrtf(vs * (1.0f / 256.0f) + 1e-5f);
#pragma unroll
    for (int ii = 0; ii < 4; ++ii) {
        int d = lane + 64 * ii;
        Y[(size_t)row * Dn + d] = f2b((x[ii] - mu) * rs * g[d] + bta[d]);
    }
}

// ---------------------------------------------------------------------------
__global__ __launch_bounds__(256) void mean_part_k(const ushort* __restrict__ Hb,
                                                   float* __restrict__ part) {
    int blk = blockIdx.x;            // 64 = 4 b x 16 groups
    int b = blk >> 4, g = blk & 15;
    int d = threadIdx.x;
    float s = 0.f;
#pragma unroll
    for (int r = 0; r < 64; ++r)
        s += b2f(Hb[(size_t)(b * Ln + g * 64 + r) * Dn + d]);
    part[(size_t)blk * Dn + d] = s;
}
__global__ __launch_bounds__(256) void mean_final_k(const float* __restrict__ part,
                                                    float* __restrict__ out) {
    int b = blockIdx.x, d = threadIdx.x;
    float s = 0.f;
#pragma unroll
    for (int g = 0; g < 16; ++g) s += part[(size_t)(b * 16 + g) * Dn + d];
    out[b * Dn + d] = s * (1.0f / (float)Ln);
}

// ---------------------------------------------------------------------------
extern "C" void kernel_launch(void* const* d_in, const int* in_sizes, int n_in,
                              void* d_out, int out_size, void* d_ws, size_t ws_size,
                              hipStream_t stream) {
    const float* x    = (const float*)d_in[0];
    const float* emb  = (const float*)d_in[1];
    const float* Wq   = (const float*)d_in[2];
    const float* bq   = (const float*)d_in[3];
    const float* Wk   = (const float*)d_in[4];
    const float* bk   = (const float*)d_in[5];
    const float* Wv   = (const float*)d_in[6];
    const float* bv   = (const float*)d_in[7];
    const float* Wo   = (const float*)d_in[8];
    const float* bo   = (const float*)d_in[9];
    const float* rk   = (const float*)d_in[10];
    const float* rb   = (const float*)d_in[11];
    const float* ln1g = (const float*)d_in[12];
    const float* ln1b = (const float*)d_in[13];
    const float* W1   = (const float*)d_in[14];
    const float* b1   = (const float*)d_in[15];
    const float* W2   = (const float*)d_in[16];
    const float* b2   = (const float*)d_in[17];
    const float* ln2g = (const float*)d_in[18];
    const float* ln2b = (const float*)d_in[19];

    float* out = (float*)d_out;
    float* avg = out + Bn * Dn;

    char* ws = (char*)d_ws;
    const size_t MB = 1024 * 1024;
    ushort* hb   = (ushort*)(ws);             // 2 MB
    ushort* qkvb = (ushort*)(ws + 2 * MB);    // 6 MB
    ushort* ctxb = (ushort*)(ws + 8 * MB);    // 2 MB
    ushort* t1   = (ushort*)(ws + 10 * MB);   // 2 MB
    ushort* ffb  = (ushort*)(ws + 12 * MB);   // 8 MB
    ushort* qkvT = (ushort*)(ws + 20 * MB);   // 1.5 MB
    ushort* WoT  = (ushort*)(ws + 22 * MB);   // 0.5 MB
    ushort* W1T  = (ushort*)(ws + 23 * MB);   // 2 MB
    ushort* W2T  = (ushort*)(ws + 25 * MB);   // 2 MB
    float*  bqkv = (float*)(ws + 27 * MB);
    float*  bkT  = (float*)(ws + 27 * MB + 65536);
    float*  bbT  = (float*)(ws + 27 * MB + 131072);
    ushort* Vt   = (ushort*)(ws + 30 * MB);   // 2 MB
    float*  mpart= (float*)(ws + 33 * MB);    // 64 KB

    embed_k<<<NTOK, 256, 0, stream>>>(x, emb, hb);
    relbias_k<<<64, 256, 0, stream>>>(rk, rb, bkT, bbT);
    prep_bias<<<12, 256, 0, stream>>>(bq, bk, bv, bqkv);

    dim3 t88(8, 8, NLn);
    transpose_cvt<<<t88, 256, 0, stream>>>(Wq, qkvT + 0,      256, 256, 65536, 196608);
    transpose_cvt<<<t88, 256, 0, stream>>>(Wk, qkvT + 65536,  256, 256, 65536, 196608);
    transpose_cvt<<<t88, 256, 0, stream>>>(Wv, qkvT + 131072, 256, 256, 65536, 196608);
    transpose_cvt<<<t88, 256, 0, stream>>>(Wo, WoT,           256, 256, 65536, 65536);
    transpose_cvt<<<dim3(32, 8, NLn), 256, 0, stream>>>(W1, W1T, 256, 1024, 262144, 262144);
    transpose_cvt<<<dim3(8, 32, NLn), 256, 0, stream>>>(W2, W2T, 1024, 256, 262144, 262144);

    for (int l = 0; l < NLn; ++l) {
        gemm_mfma<<<dim3(12, 64), 256, 0, stream>>>(
            hb, qkvT + (size_t)l * 196608, bqkv + l * QKVW, qkvb, NTOK, QKVW, Dn, 0);
        transpose_v<<<dim3(32, 16), 256, 0, stream>>>(qkvb, Vt);
        attn_fused<<<1024, 256, 0, stream>>>(
            qkvb, Vt, bkT + l * Hn * Ln, bbT + l * Hn * Ln, ctxb, avg, (l == 0) ? 1 : 0);
        gemm_mfma<<<dim3(4, 64), 256, 0, stream>>>(
            ctxb, WoT + (size_t)l * 65536, bo + l * 256, t1, NTOK, Dn, Dn, 0);
        layernorm_k<<<NTOK / 4, 256, 0, stream>>>(
            t1, ln1g + l * 256, ln1b + l * 256, t1);
        gemm_mfma<<<dim3(16, 64), 256, 0, stream>>>(
            t1, W1T + (size_t)l * 262144, b1 + l * FFn, ffb, NTOK, FFn, Dn, 1);
        gemm_mfma<<<dim3(4, 64), 256, 0, stream>>>(
            ffb, W2T + (size_t)l * 262144, b2 + l * 256, hb, NTOK, Dn, FFn, 0);
        layernorm_k<<<NTOK / 4, 256, 0, stream>>>(
            hb, ln2g + l * 256, ln2b + l * 256, hb);
    }
    mean_part_k<<<64, 256, 0, stream>>>(hb, mpart);
    mean_final_k<<<Bn, 256, 0, stream>>>(mpart, out);
}

// Round 6
// 460.994 us; speedup vs baseline: 3.2690x; 1.1269x over previous
//
#include <hip/hip_runtime.h>
#include <hip/hip_bf16.h>
#include <math.h>

// Problem constants
#define Bn 4
#define Ln 1024
#define Vn 64
#define Dn 256
#define Hn 4
#define DKn 64
#define NLn 4
#define Mn 20
#define FFn 1024
#define NTOK (Bn * Ln)   // 4096
#define QKVW 768         // fused q|k|v width
#define LOG2E 1.4426950408889634f

typedef __attribute__((ext_vector_type(8))) short bf16x8;
typedef __attribute__((ext_vector_type(4))) float f32x4;

__device__ __forceinline__ ushort f2b(float f) {   // fp32 -> bf16 RNE
    uint u = __float_as_uint(f);
    u += 0x7fff + ((u >> 16) & 1);
    return (ushort)(u >> 16);
}
__device__ __forceinline__ float b2f(ushort u) {   // exact
    return __uint_as_float(((uint)u) << 16);
}

// ---------------------------------------------------------------------------
__global__ __launch_bounds__(256) void embed_k(const float* __restrict__ X,
                                               const float* __restrict__ E,
                                               ushort* __restrict__ Hb) {
    __shared__ float xs[Vn];
    int n = blockIdx.x, d = threadIdx.x;
    if (threadIdx.x < Vn) xs[threadIdx.x] = X[n * Vn + threadIdx.x];
    __syncthreads();
    float s = 0.f;
#pragma unroll
    for (int v = 0; v < Vn; ++v) s += xs[v] * E[v * Dn + d];
    Hb[(size_t)n * Dn + d] = f2b(s);
}

// ---------------------------------------------------------------------------
// bias tables, pre-scaled into exp2 domain:
//   bkT = rel_k * 0.125 * log2(e);  bbT = rel_b * log2(e)
__global__ __launch_bounds__(256) void relbias_k(const float* __restrict__ rk,
                                                 const float* __restrict__ rb,
                                                 float* __restrict__ bkT,
                                                 float* __restrict__ bbT) {
    int tid = blockIdx.x * 256 + threadIdx.x;   // < NL*H*1024
    int dist = tid & 1023;
    int hh = (tid >> 10) & 3;
    int l = tid >> 12;
    float dd = (float)dist;
    if (dist > Mn) dd = (float)Mn + log2f((float)(dist - Mn));
    if (dd > 2.0f * Mn) dd = 2.0f * Mn;
    int idx = (int)dd;
    bkT[tid] = rk[(l * (2 * Mn + 1) + idx) * Hn + hh] * 0.125f * LOG2E;
    bbT[tid] = rb[(l * (2 * Mn + 1) + idx) * Hn + hh] * LOG2E;
}

// ---------------------------------------------------------------------------
__global__ __launch_bounds__(256) void prep_bias(const float* __restrict__ bq,
                                                 const float* __restrict__ bk,
                                                 const float* __restrict__ bv,
                                                 float* __restrict__ bqkv) {
    int idx = blockIdx.x * 256 + threadIdx.x;   // < NL*768
    int l = idx / QKVW, r = idx - l * QKVW;
    float v;
    if (r < 256)      v = bq[l * 256 + r];
    else if (r < 512) v = bk[l * 256 + r - 256];
    else              v = bv[l * 256 + r - 512];
    bqkv[idx] = v;
}

// ---------------------------------------------------------------------------
// Weight transpose + fp32->bf16: dst[c][r] = src[r][c]; grid.z = layer.
__global__ __launch_bounds__(256) void transpose_cvt(
    const float* __restrict__ src, ushort* __restrict__ dst,
    int R, int C, int srcLS, int dstLS) {
    __shared__ float s[32][33];
    src += (size_t)blockIdx.z * srcLS;
    dst += (size_t)blockIdx.z * dstLS;
    int r0 = blockIdx.y * 32, c0 = blockIdx.x * 32;
    int tx = threadIdx.x & 31, ty = threadIdx.x >> 5;
#pragma unroll
    for (int ii = 0; ii < 4; ++ii)
        s[ty + 8 * ii][tx] = src[(size_t)(r0 + ty + 8 * ii) * C + c0 + tx];
    __syncthreads();
#pragma unroll
    for (int ii = 0; ii < 4; ++ii)
        dst[(size_t)(c0 + ty + 8 * ii) * R + r0 + tx] = f2b(s[tx][ty + 8 * ii]);
}

// ---------------------------------------------------------------------------
// V transpose per (b,h): Vt[bh][d][j] = qkvb[b*L+j][512 + h*64 + d]
__global__ __launch_bounds__(256) void transpose_v(const ushort* __restrict__ qkv,
                                                   ushort* __restrict__ Vt) {
    __shared__ ushort s[32][65];
    int j0 = blockIdx.x * 32;
    int bh = blockIdx.y;
    int b = bh >> 2, hh = bh & 3;
    int t = threadIdx.x;
#pragma unroll
    for (int ii = 0; ii < 8; ++ii) {
        int e = t + 256 * ii;          // 2048 = 32 j x 64 d
        int jr = e >> 6, dc = e & 63;
        s[jr][dc] = qkv[(size_t)(b * Ln + j0 + jr) * QKVW + 2 * Dn + hh * DKn + dc];
    }
    __syncthreads();
#pragma unroll
    for (int ii = 0; ii < 8; ++ii) {
        int e = t + 256 * ii;          // 2048 = 64 d x 32 j
        int dr = e >> 5, jc = e & 31;
        Vt[(size_t)(bh * DKn + dr) * Ln + j0 + jc] = s[jc][dr];
    }
}

// ---------------------------------------------------------------------------
// bf16 MFMA GEMM: C[m][n] = act(sum_k A[m][k]*Bt[n][k] + bias[n]), C bf16.
#define GST 40
__global__ __launch_bounds__(256) void gemm_mfma(
    const ushort* __restrict__ A, const ushort* __restrict__ Bt,
    const float* __restrict__ bias, ushort* __restrict__ C,
    int M, int N, int K, int act) {
    __shared__ __align__(16) ushort As[64 * GST];
    __shared__ __align__(16) ushort Bs[64 * GST];
    int t = threadIdx.x;
    int lane = t & 63, w = t >> 6;
    int wm = w >> 1, wn = w & 1;
    int l15 = lane & 15, lg = lane >> 4;
    int mBase = blockIdx.y * 64, nBase = blockIdx.x * 64;
    int lrow = t >> 2, lkc = (t & 3) * 8;
    const ushort* Ap = A + (size_t)(mBase + lrow) * K + lkc;
    const ushort* Bp = Bt + (size_t)(nBase + lrow) * K + lkc;
    f32x4 acc[2][2] = {};
    for (int k0 = 0; k0 < K; k0 += 32) {
        uint4 av = *(const uint4*)(Ap + k0);
        uint4 bv = *(const uint4*)(Bp + k0);
        __syncthreads();
        *(uint4*)&As[lrow * GST + lkc] = av;
        *(uint4*)&Bs[lrow * GST + lkc] = bv;
        __syncthreads();
        bf16x8 a0 = *(const bf16x8*)&As[(wm * 32 + l15) * GST + lg * 8];
        bf16x8 a1 = *(const bf16x8*)&As[(wm * 32 + 16 + l15) * GST + lg * 8];
        bf16x8 b0 = *(const bf16x8*)&Bs[(wn * 32 + l15) * GST + lg * 8];
        bf16x8 b1 = *(const bf16x8*)&Bs[(wn * 32 + 16 + l15) * GST + lg * 8];
        acc[0][0] = __builtin_amdgcn_mfma_f32_16x16x32_bf16(a0, b0, acc[0][0], 0, 0, 0);
        acc[0][1] = __builtin_amdgcn_mfma_f32_16x16x32_bf16(a0, b1, acc[0][1], 0, 0, 0);
        acc[1][0] = __builtin_amdgcn_mfma_f32_16x16x32_bf16(a1, b0, acc[1][0], 0, 0, 0);
        acc[1][1] = __builtin_amdgcn_mfma_f32_16x16x32_bf16(a1, b1, acc[1][1], 0, 0, 0);
    }
#pragma unroll
    for (int ni = 0; ni < 2; ++ni) {
        int col = nBase + wn * 32 + ni * 16 + l15;
        float bc = bias[col];
#pragma unroll
        for (int mi = 0; mi < 2; ++mi) {
            int rb = mBase + wm * 32 + mi * 16 + lg * 4;
#pragma unroll
            for (int j = 0; j < 4; ++j) {
                float v = acc[mi][ni][j] + bc;
                if (act) v = v * 0.5f * (1.0f + erff(v * 0.7071067811865475f));
                C[(size_t)(rb + j) * N + col] = f2b(v);
            }
        }
    }
}

// ---------------------------------------------------------------------------
// MFMA flash attention, single QK pass, scores in registers.
// avg RMW is staged through LDS (Pf) so each wave RMWs 256B-contiguous
// segments, interleaved with PV MFMAs inside the same barrier window.
#define PFST 65
__global__ __launch_bounds__(256) void attn_fused(
    const ushort* __restrict__ qkv, const ushort* __restrict__ Vt,
    const float* __restrict__ bkTab, const float* __restrict__ bbTab,
    ushort* __restrict__ ctx, float* __restrict__ avg, int first) {
    __shared__ float bk_l[Ln];
    __shared__ float bb_l[Ln];
    __shared__ __align__(16) ushort Ps[16 * 64];   // P hi, XOR-swizzled
    __shared__ __align__(16) ushort Pl[16 * 64];   // P lo
    __shared__ float Pf[16 * PFST];                // P f32, padded
    __shared__ float mm[4][16];
    __shared__ float ll[4][16];

    int t = threadIdx.x;
    int lane = t & 63, wn = t >> 6;       // wave = column quarter
    int l15 = lane & 15, lg = lane >> 4;

    int bid = blockIdx.x;
    int xcd = bid & 7, sub = bid >> 3;    // sub in [0,128)
    int bh = xcd * 2 + (sub >> 6);
    int q = sub & 63;
    int b = bh >> 2, hh = bh & 3;
    int i0 = q * 16;

#pragma unroll
    for (int ii = 0; ii < 4; ++ii) {
        bk_l[t + 256 * ii] = bkTab[hh * Ln + t + 256 * ii];
        bb_l[t + 256 * ii] = bbTab[hh * Ln + t + 256 * ii];
    }
    __syncthreads();

    // Q fragment (A-operand): row = i0 + l15, k = lg*8 (+32)
    bf16x8 qa0, qa1;
    {
        const ushort* qp = qkv + (size_t)(b * Ln + i0 + l15) * QKVW + hh * DKn;
        qa0 = *(const bf16x8*)(qp + lg * 8);
        qa1 = *(const bf16x8*)(qp + 32 + lg * 8);
    }

    const ushort* kbase = qkv + (size_t)(b * Ln) * QKVW + Dn + hh * DKn;

    // ---- QK pass: S kept in registers (fully unrolled -> static idx) -------
    f32x4 sv[16];
    float m[4] = {-1e30f, -1e30f, -1e30f, -1e30f};
#pragma unroll
    for (int c = 0; c < 16; ++c) {
        const ushort* kp = kbase + (size_t)(c * 64 + wn * 16 + l15) * QKVW;
        bf16x8 k0 = *(const bf16x8*)(kp + lg * 8);
        bf16x8 k1 = *(const bf16x8*)(kp + 32 + lg * 8);
        f32x4 acc = {};
        acc = __builtin_amdgcn_mfma_f32_16x16x32_bf16(qa0, k0, acc, 0, 0, 0);
        acc = __builtin_amdgcn_mfma_f32_16x16x32_bf16(qa1, k1, acc, 0, 0, 0);
        int j = c * 64 + wn * 16 + l15;
#pragma unroll
        for (int r = 0; r < 4; ++r) {
            int i = i0 + lg * 4 + r;
            int dist = (i > j) ? (i - j) : (j - i);
            float s = acc[r] * bk_l[dist] + bb_l[dist];
            sv[c][r] = s;
            m[r] = fmaxf(m[r], s);
        }
    }
    // merge max over the 16 l15-lanes
#pragma unroll
    for (int mask = 1; mask < 16; mask <<= 1)
#pragma unroll
        for (int r = 0; r < 4; ++r) m[r] = fmaxf(m[r], __shfl_xor(m[r], mask, 64));
    // merge max across the 4 waves
    if (l15 == 0)
#pragma unroll
        for (int r = 0; r < 4; ++r) mm[wn][lg * 4 + r] = m[r];
    __syncthreads();
#pragma unroll
    for (int r = 0; r < 4; ++r) {
        int row = lg * 4 + r;
        m[r] = fmaxf(fmaxf(mm[0][row], mm[1][row]), fmaxf(mm[2][row], mm[3][row]));
    }
    // p_unnorm = exp2(s - m); accumulate row sums
    float lsum[4] = {0.f, 0.f, 0.f, 0.f};
#pragma unroll
    for (int c = 0; c < 16; ++c)
#pragma unroll
        for (int r = 0; r < 4; ++r) {
            float p = exp2f(sv[c][r] - m[r]);
            sv[c][r] = p;
            lsum[r] += p;
        }
#pragma unroll
    for (int mask = 1; mask < 16; mask <<= 1)
#pragma unroll
        for (int r = 0; r < 4; ++r) lsum[r] += __shfl_xor(lsum[r], mask, 64);
    if (l15 == 0)
#pragma unroll
        for (int r = 0; r < 4; ++r) ll[wn][lg * 4 + r] = lsum[r];
    __syncthreads();
    float invl[4];
#pragma unroll
    for (int r = 0; r < 4; ++r) {
        int row = lg * 4 + r;
        invl[r] = 1.0f / (ll[0][row] + ll[1][row] + ll[2][row] + ll[3][row]);
    }

    // ---- fused PV + avg RMW --------------------------------------------------
    const ushort* vtb = Vt + ((size_t)bh * DKn + wn * 16 + l15) * Ln;
    float* avgrow = avg + ((size_t)bh * Ln + i0) * Ln;   // [16][1024] slice
    f32x4 acco = {};
#pragma unroll
    for (int c = 0; c < 16; ++c) {
        // stage P: bf16 hi/lo (swizzled, for MFMA) + f32 (padded, for avg)
#pragma unroll
        for (int r = 0; r < 4; ++r) {
            int row = lg * 4 + r;
            float p = sv[c][r] * invl[r];
            ushort ph = f2b(p);
            int byte = row * 128 + (((wn * 16 + l15) * 2) ^ ((row & 7) << 4));
            *(ushort*)((char*)Ps + byte) = ph;
            *(ushort*)((char*)Pl + byte) = f2b(p - b2f(ph));
            Pf[row * PFST + wn * 16 + l15] = p;
        }
        // V loads in flight across the barrier
        bf16x8 v0 = *(const bf16x8*)(vtb + c * 64 + lg * 8);
        bf16x8 v1 = *(const bf16x8*)(vtb + c * 64 + 32 + lg * 8);
        __syncthreads();   // P tiles ready
        bf16x8 pbh[2], pbl[2];
#pragma unroll
        for (int kc = 0; kc < 2; ++kc) {
            int byte = l15 * 128 + (((kc * 4 + lg) * 16) ^ ((l15 & 7) << 4));
            pbh[kc] = *(const bf16x8*)((char*)Ps + byte);
            pbl[kc] = *(const bf16x8*)((char*)Pl + byte);
        }
        acco = __builtin_amdgcn_mfma_f32_16x16x32_bf16(v0, pbh[0], acco, 0, 0, 0);
        acco = __builtin_amdgcn_mfma_f32_16x16x32_bf16(v1, pbh[1], acco, 0, 0, 0);
        acco = __builtin_amdgcn_mfma_f32_16x16x32_bf16(v0, pbl[0], acco, 0, 0, 0);
        acco = __builtin_amdgcn_mfma_f32_16x16x32_bf16(v1, pbl[1], acco, 0, 0, 0);
        // avg RMW: wave wn owns rows wn*4..wn*4+3; 64 lanes = 256B contiguous
        if (first) {
#pragma unroll
            for (int rr = 0; rr < 4; ++rr) {
                int row = wn * 4 + rr;
                avgrow[(size_t)row * Ln + c * 64 + lane] =
                    0.25f * Pf[row * PFST + lane];
            }
        } else {
#pragma unroll
            for (int rr = 0; rr < 4; ++rr) {
                int row = wn * 4 + rr;
                avgrow[(size_t)row * Ln + c * 64 + lane] +=
                    0.25f * Pf[row * PFST + lane];
            }
        }
        __syncthreads();   // all reads done before next chunk's stores
    }

    // O^T[d = wn*16+lg*4+r][qrow = l15] -> ctx[i0+l15][hh*64 + d]
    {
        uint lo = (uint)f2b(acco[0]) | ((uint)f2b(acco[1]) << 16);
        uint hi = (uint)f2b(acco[2]) | ((uint)f2b(acco[3]) << 16);
        uint2 pk = make_uint2(lo, hi);
        *(uint2*)&ctx[(size_t)(b * Ln + i0 + l15) * Dn + hh * DKn + wn * 16 + lg * 4] = pk;
    }
}

// ---------------------------------------------------------------------------
__global__ __launch_bounds__(256) void layernorm_k(const ushort* __restrict__ X,
                                                   const float* __restrict__ g,
                                                   const float* __restrict__ bta,
                                                   ushort* __restrict__ Y) {
    int w = threadIdx.x >> 6, lane = threadIdx.x & 63;
    int row = blockIdx.x * 4 + w;
    const ushort* xr = X + (size_t)row * Dn;
    float x[4];
#pragma unroll
    for (int ii = 0; ii < 4; ++ii) x[ii] = b2f(xr[lane + 64 * ii]);
    float s = x[0] + x[1] + x[2] + x[3];
#pragma unroll
    for (int m = 1; m < 64; m <<= 1) s += __shfl_xor(s, m, 64);
    float mu = s * (1.0f / 256.0f);
    float vs = 0.f;
#pragma unroll
    for (int ii = 0; ii < 4; ++ii) {
        float d = x[ii] - mu;
        vs += d * d;
    }
#pragma unroll
    for (int m = 1; m < 64; m <<= 1) vs += __shfl_xor(vs, m, 64);
    float rs = rsqrtf(vs * (1.0f / 256.0f) + 1e-5f);
#pragma unroll
    for (int ii = 0; ii < 4; ++ii) {
        int d = lane + 64 * ii;
        Y[(size_t)row * Dn + d] = f2b((x[ii] - mu) * rs * g[d] + bta[d]);
    }
}

// ---------------------------------------------------------------------------
__global__ __launch_bounds__(256) void mean_part_k(const ushort* __restrict__ Hb,
                                                   float* __restrict__ part) {
    int blk = blockIdx.x;            // 64 = 4 b x 16 groups
    int b = blk >> 4, g = blk & 15;
    int d = threadIdx.x;
    float s = 0.f;
#pragma unroll
    for (int r = 0; r < 64; ++r)
        s += b2f(Hb[(size_t)(b * Ln + g * 64 + r) * Dn + d]);
    part[(size_t)blk * Dn + d] = s;
}
__global__ __launch_bounds__(256) void mean_final_k(const float* __restrict__ part,
                                                    float* __restrict__ out) {
    int b = blockIdx.x, d = threadIdx.x;
    float s = 0.f;
#pragma unroll
    for (int g = 0; g < 16; ++g) s += part[(size_t)(b * 16 + g) * Dn + d];
    out[b * Dn + d] = s * (1.0f / (float)Ln);
}

// ---------------------------------------------------------------------------
extern "C" void kernel_launch(void* const* d_in, const int* in_sizes, int n_in,
                              void* d_out, int out_size, void* d_ws, size_t ws_size,
                              hipStream_t stream) {
    const float* x    = (const float*)d_in[0];
    const float* emb  = (const float*)d_in[1];
    const float* Wq   = (const float*)d_in[2];
    const float* bq   = (const float*)d_in[3];
    const float* Wk   = (const float*)d_in[4];
    const float* bk   = (const float*)d_in[5];
    const float* Wv   = (const float*)d_in[6];
    const float* bv   = (const float*)d_in[7];
    const float* Wo   = (const float*)d_in[8];
    const float* bo   = (const float*)d_in[9];
    const float* rk   = (const float*)d_in[10];
    const float* rb   = (const float*)d_in[11];
    const float* ln1g = (const float*)d_in[12];
    const float* ln1b = (const float*)d_in[13];
    const float* W1   = (const float*)d_in[14];
    const float* b1   = (const float*)d_in[15];
    const float* W2   = (const float*)d_in[16];
    const float* b2   = (const float*)d_in[17];
    const float* ln2g = (const float*)d_in[18];
    const float* ln2b = (const float*)d_in[19];

    float* out = (float*)d_out;
    float* avg = out + Bn * Dn;

    char* ws = (char*)d_ws;
    const size_t MB = 1024 * 1024;
    ushort* hb   = (ushort*)(ws);             // 2 MB
    ushort* qkvb = (ushort*)(ws + 2 * MB);    // 6 MB
    ushort* ctxb = (ushort*)(ws + 8 * MB);    // 2 MB
    ushort* t1   = (ushort*)(ws + 10 * MB);   // 2 MB
    ushort* ffb  = (ushort*)(ws + 12 * MB);   // 8 MB
    ushort* qkvT = (ushort*)(ws + 20 * MB);   // 1.5 MB
    ushort* WoT  = (ushort*)(ws + 22 * MB);   // 0.5 MB
    ushort* W1T  = (ushort*)(ws + 23 * MB);   // 2 MB
    ushort* W2T  = (ushort*)(ws + 25 * MB);   // 2 MB
    float*  bqkv = (float*)(ws + 27 * MB);
    float*  bkT  = (float*)(ws + 27 * MB + 65536);
    float*  bbT  = (float*)(ws + 27 * MB + 131072);
    ushort* Vt   = (ushort*)(ws + 30 * MB);   // 2 MB
    float*  mpart= (float*)(ws + 33 * MB);    // 64 KB

    embed_k<<<NTOK, 256, 0, stream>>>(x, emb, hb);
    relbias_k<<<64, 256, 0, stream>>>(rk, rb, bkT, bbT);
    prep_bias<<<12, 256, 0, stream>>>(bq, bk, bv, bqkv);

    dim3 t88(8, 8, NLn);
    transpose_cvt<<<t88, 256, 0, stream>>>(Wq, qkvT + 0,      256, 256, 65536, 196608);
    transpose_cvt<<<t88, 256, 0, stream>>>(Wk, qkvT + 65536,  256, 256, 65536, 196608);
    transpose_cvt<<<t88, 256, 0, stream>>>(Wv, qkvT + 131072, 256, 256, 65536, 196608);
    transpose_cvt<<<t88, 256, 0, stream>>>(Wo, WoT,           256, 256, 65536, 65536);
    transpose_cvt<<<dim3(32, 8, NLn), 256, 0, stream>>>(W1, W1T, 256, 1024, 262144, 262144);
    transpose_cvt<<<dim3(8, 32, NLn), 256, 0, stream>>>(W2, W2T, 1024, 256, 262144, 262144);

    for (int l = 0; l < NLn; ++l) {
        gemm_mfma<<<dim3(12, 64), 256, 0, stream>>>(
            hb, qkvT + (size_t)l * 196608, bqkv + l * QKVW, qkvb, NTOK, QKVW, Dn, 0);
        transpose_v<<<dim3(32, 16), 256, 0, stream>>>(qkvb, Vt);
        attn_fused<<<1024, 256, 0, stream>>>(
            qkvb, Vt, bkT + l * Hn * Ln, bbT + l * Hn * Ln, ctxb, avg, (l == 0) ? 1 : 0);
        gemm_mfma<<<dim3(4, 64), 256, 0, stream>>>(
            ctxb, WoT + (size_t)l * 65536, bo + l * 256, t1, NTOK, Dn, Dn, 0);
        layernorm_k<<<NTOK / 4, 256, 0, stream>>>(
            t1, ln1g + l * 256, ln1b + l * 256, t1);
        gemm_mfma<<<dim3(16, 64), 256, 0, stream>>>(
            t1, W1T + (size_t)l * 262144, b1 + l * FFn, ffb, NTOK, FFn, Dn, 1);
        gemm_mfma<<<dim3(4, 64), 256, 0, stream>>>(
            ffb, W2T + (size_t)l * 262144, b2 + l * 256, hb, NTOK, Dn, FFn, 0);
        layernorm_k<<<NTOK / 4, 256, 0, stream>>>(
            hb, ln2g + l * 256, ln2b + l * 256, hb);
    }
    mean_part_k<<<64, 256, 0, stream>>>(hb, mpart);
    mean_final_k<<<Bn, 256, 0, stream>>>(mpart, out);
}

// Round 7
// 438.460 us; speedup vs baseline: 3.4370x; 1.0514x over previous
//
#include <hip/hip_runtime.h>
#include <hip/hip_bf16.h>
#include <math.h>

// Problem constants
#define Bn 4
#define Ln 1024
#define Vn 64
#define Dn 256
#define Hn 4
#define DKn 64
#define NLn 4
#define Mn 20
#define FFn 1024
#define NTOK (Bn * Ln)   // 4096
#define QKVW 768         // fused q|k|v width
#define LOG2E 1.4426950408889634f

typedef __attribute__((ext_vector_type(8))) short bf16x8;
typedef __attribute__((ext_vector_type(4))) float f32x4;

__device__ __forceinline__ ushort f2b(float f) {   // fp32 -> bf16 RNE
    uint u = __float_as_uint(f);
    u += 0x7fff + ((u >> 16) & 1);
    return (ushort)(u >> 16);
}
__device__ __forceinline__ float b2f(ushort u) {   // exact
    return __uint_as_float(((uint)u) << 16);
}

// ---------------------------------------------------------------------------
__global__ __launch_bounds__(256) void embed_k(const float* __restrict__ X,
                                               const float* __restrict__ E,
                                               ushort* __restrict__ Hb) {
    __shared__ float xs[Vn];
    int n = blockIdx.x, d = threadIdx.x;
    if (threadIdx.x < Vn) xs[threadIdx.x] = X[n * Vn + threadIdx.x];
    __syncthreads();
    float s = 0.f;
#pragma unroll
    for (int v = 0; v < Vn; ++v) s += xs[v] * E[v * Dn + d];
    Hb[(size_t)n * Dn + d] = f2b(s);
}

// ---------------------------------------------------------------------------
// bias tables, pre-scaled into exp2 domain:
//   bkT = rel_k * 0.125 * log2(e);  bbT = rel_b * log2(e)
__global__ __launch_bounds__(256) void relbias_k(const float* __restrict__ rk,
                                                 const float* __restrict__ rb,
                                                 float* __restrict__ bkT,
                                                 float* __restrict__ bbT) {
    int tid = blockIdx.x * 256 + threadIdx.x;   // < NL*H*1024
    int dist = tid & 1023;
    int hh = (tid >> 10) & 3;
    int l = tid >> 12;
    float dd = (float)dist;
    if (dist > Mn) dd = (float)Mn + log2f((float)(dist - Mn));
    if (dd > 2.0f * Mn) dd = 2.0f * Mn;
    int idx = (int)dd;
    bkT[tid] = rk[(l * (2 * Mn + 1) + idx) * Hn + hh] * 0.125f * LOG2E;
    bbT[tid] = rb[(l * (2 * Mn + 1) + idx) * Hn + hh] * LOG2E;
}

// ---------------------------------------------------------------------------
__global__ __launch_bounds__(256) void prep_bias(const float* __restrict__ bq,
                                                 const float* __restrict__ bk,
                                                 const float* __restrict__ bv,
                                                 float* __restrict__ bqkv) {
    int idx = blockIdx.x * 256 + threadIdx.x;   // < NL*768
    int l = idx / QKVW, r = idx - l * QKVW;
    float v;
    if (r < 256)      v = bq[l * 256 + r];
    else if (r < 512) v = bk[l * 256 + r - 256];
    else              v = bv[l * 256 + r - 512];
    bqkv[idx] = v;
}

// ---------------------------------------------------------------------------
// Weight transpose + fp32->bf16: dst[c][r] = src[r][c]; grid.z = layer.
__global__ __launch_bounds__(256) void transpose_cvt(
    const float* __restrict__ src, ushort* __restrict__ dst,
    int R, int C, int srcLS, int dstLS) {
    __shared__ float s[32][33];
    src += (size_t)blockIdx.z * srcLS;
    dst += (size_t)blockIdx.z * dstLS;
    int r0 = blockIdx.y * 32, c0 = blockIdx.x * 32;
    int tx = threadIdx.x & 31, ty = threadIdx.x >> 5;
#pragma unroll
    for (int ii = 0; ii < 4; ++ii)
        s[ty + 8 * ii][tx] = src[(size_t)(r0 + ty + 8 * ii) * C + c0 + tx];
    __syncthreads();
#pragma unroll
    for (int ii = 0; ii < 4; ++ii)
        dst[(size_t)(c0 + ty + 8 * ii) * R + r0 + tx] = f2b(s[tx][ty + 8 * ii]);
}

// ---------------------------------------------------------------------------
// V transpose per (b,h): Vt[bh][d][j] = qkvb[b*L+j][512 + h*64 + d]
__global__ __launch_bounds__(256) void transpose_v(const ushort* __restrict__ qkv,
                                                   ushort* __restrict__ Vt) {
    __shared__ ushort s[32][65];
    int j0 = blockIdx.x * 32;
    int bh = blockIdx.y;
    int b = bh >> 2, hh = bh & 3;
    int t = threadIdx.x;
#pragma unroll
    for (int ii = 0; ii < 8; ++ii) {
        int e = t + 256 * ii;          // 2048 = 32 j x 64 d
        int jr = e >> 6, dc = e & 63;
        s[jr][dc] = qkv[(size_t)(b * Ln + j0 + jr) * QKVW + 2 * Dn + hh * DKn + dc];
    }
    __syncthreads();
#pragma unroll
    for (int ii = 0; ii < 8; ++ii) {
        int e = t + 256 * ii;          // 2048 = 64 d x 32 j
        int dr = e >> 5, jc = e & 31;
        Vt[(size_t)(bh * DKn + dr) * Ln + j0 + jc] = s[jc][dr];
    }
}

// ---------------------------------------------------------------------------
// bf16 MFMA GEMM: C[m][n] = act(sum_k A[m][k]*Bt[n][k] + bias[n]), C bf16.
#define GST 40
__global__ __launch_bounds__(256) void gemm_mfma(
    const ushort* __restrict__ A, const ushort* __restrict__ Bt,
    const float* __restrict__ bias, ushort* __restrict__ C,
    int M, int N, int K, int act) {
    __shared__ __align__(16) ushort As[64 * GST];
    __shared__ __align__(16) ushort Bs[64 * GST];
    int t = threadIdx.x;
    int lane = t & 63, w = t >> 6;
    int wm = w >> 1, wn = w & 1;
    int l15 = lane & 15, lg = lane >> 4;
    int mBase = blockIdx.y * 64, nBase = blockIdx.x * 64;
    int lrow = t >> 2, lkc = (t & 3) * 8;
    const ushort* Ap = A + (size_t)(mBase + lrow) * K + lkc;
    const ushort* Bp = Bt + (size_t)(nBase + lrow) * K + lkc;
    f32x4 acc[2][2] = {};
    for (int k0 = 0; k0 < K; k0 += 32) {
        uint4 av = *(const uint4*)(Ap + k0);
        uint4 bv = *(const uint4*)(Bp + k0);
        __syncthreads();
        *(uint4*)&As[lrow * GST + lkc] = av;
        *(uint4*)&Bs[lrow * GST + lkc] = bv;
        __syncthreads();
        bf16x8 a0 = *(const bf16x8*)&As[(wm * 32 + l15) * GST + lg * 8];
        bf16x8 a1 = *(const bf16x8*)&As[(wm * 32 + 16 + l15) * GST + lg * 8];
        bf16x8 b0 = *(const bf16x8*)&Bs[(wn * 32 + l15) * GST + lg * 8];
        bf16x8 b1 = *(const bf16x8*)&Bs[(wn * 32 + 16 + l15) * GST + lg * 8];
        acc[0][0] = __builtin_amdgcn_mfma_f32_16x16x32_bf16(a0, b0, acc[0][0], 0, 0, 0);
        acc[0][1] = __builtin_amdgcn_mfma_f32_16x16x32_bf16(a0, b1, acc[0][1], 0, 0, 0);
        acc[1][0] = __builtin_amdgcn_mfma_f32_16x16x32_bf16(a1, b0, acc[1][0], 0, 0, 0);
        acc[1][1] = __builtin_amdgcn_mfma_f32_16x16x32_bf16(a1, b1, acc[1][1], 0, 0, 0);
    }
#pragma unroll
    for (int ni = 0; ni < 2; ++ni) {
        int col = nBase + wn * 32 + ni * 16 + l15;
        float bc = bias[col];
#pragma unroll
        for (int mi = 0; mi < 2; ++mi) {
            int rb = mBase + wm * 32 + mi * 16 + lg * 4;
#pragma unroll
            for (int j = 0; j < 4; ++j) {
                float v = acc[mi][ni][j] + bc;
                if (act) v = v * 0.5f * (1.0f + erff(v * 0.7071067811865475f));
                C[(size_t)(rb + j) * N + col] = f2b(v);
            }
        }
    }
}

// ---------------------------------------------------------------------------
// MFMA flash attention, single QK pass, scores in registers.
// PV loop: double-buffered P tiles -> ONE barrier per chunk; avg RMW loads
// issued right after the barrier (hidden under staging+V loads+MFMA) and
// avg values recomputed in-register (no f32 LDS round-trip).
__global__ __launch_bounds__(256) void attn_fused(
    const ushort* __restrict__ qkv, const ushort* __restrict__ Vt,
    const float* __restrict__ bkTab, const float* __restrict__ bbTab,
    ushort* __restrict__ ctx, float* __restrict__ avg, int first) {
    __shared__ float bk_l[Ln];
    __shared__ float bb_l[Ln];
    __shared__ __align__(16) ushort Ps[2][16 * 64];   // P hi, XOR-swizzled, dbuf
    __shared__ __align__(16) ushort Pl[2][16 * 64];   // P lo
    __shared__ float mm[4][16];
    __shared__ float ll[4][16];

    int t = threadIdx.x;
    int lane = t & 63, wn = t >> 6;       // wave = column quarter
    int l15 = lane & 15, lg = lane >> 4;

    int bid = blockIdx.x;
    int xcd = bid & 7, sub = bid >> 3;    // sub in [0,128)
    int bh = xcd * 2 + (sub >> 6);
    int q = sub & 63;
    int b = bh >> 2, hh = bh & 3;
    int i0 = q * 16;

#pragma unroll
    for (int ii = 0; ii < 4; ++ii) {
        bk_l[t + 256 * ii] = bkTab[hh * Ln + t + 256 * ii];
        bb_l[t + 256 * ii] = bbTab[hh * Ln + t + 256 * ii];
    }
    __syncthreads();

    // Q fragment (A-operand): row = i0 + l15, k = lg*8 (+32)
    bf16x8 qa0, qa1;
    {
        const ushort* qp = qkv + (size_t)(b * Ln + i0 + l15) * QKVW + hh * DKn;
        qa0 = *(const bf16x8*)(qp + lg * 8);
        qa1 = *(const bf16x8*)(qp + 32 + lg * 8);
    }

    const ushort* kbase = qkv + (size_t)(b * Ln) * QKVW + Dn + hh * DKn;

    // ---- QK pass: S kept in registers (fully unrolled -> static idx) -------
    f32x4 sv[16];
    float m[4] = {-1e30f, -1e30f, -1e30f, -1e30f};
#pragma unroll
    for (int c = 0; c < 16; ++c) {
        const ushort* kp = kbase + (size_t)(c * 64 + wn * 16 + l15) * QKVW;
        bf16x8 k0 = *(const bf16x8*)(kp + lg * 8);
        bf16x8 k1 = *(const bf16x8*)(kp + 32 + lg * 8);
        f32x4 acc = {};
        acc = __builtin_amdgcn_mfma_f32_16x16x32_bf16(qa0, k0, acc, 0, 0, 0);
        acc = __builtin_amdgcn_mfma_f32_16x16x32_bf16(qa1, k1, acc, 0, 0, 0);
        int j = c * 64 + wn * 16 + l15;
#pragma unroll
        for (int r = 0; r < 4; ++r) {
            int i = i0 + lg * 4 + r;
            int dist = (i > j) ? (i - j) : (j - i);
            float s = acc[r] * bk_l[dist] + bb_l[dist];
            sv[c][r] = s;
            m[r] = fmaxf(m[r], s);
        }
    }
    // merge max over the 16 l15-lanes
#pragma unroll
    for (int mask = 1; mask < 16; mask <<= 1)
#pragma unroll
        for (int r = 0; r < 4; ++r) m[r] = fmaxf(m[r], __shfl_xor(m[r], mask, 64));
    // merge max across the 4 waves
    if (l15 == 0)
#pragma unroll
        for (int r = 0; r < 4; ++r) mm[wn][lg * 4 + r] = m[r];
    __syncthreads();
#pragma unroll
    for (int r = 0; r < 4; ++r) {
        int row = lg * 4 + r;
        m[r] = fmaxf(fmaxf(mm[0][row], mm[1][row]), fmaxf(mm[2][row], mm[3][row]));
    }
    // p_unnorm = exp2(s - m); accumulate row sums
    float lsum[4] = {0.f, 0.f, 0.f, 0.f};
#pragma unroll
    for (int c = 0; c < 16; ++c)
#pragma unroll
        for (int r = 0; r < 4; ++r) {
            float p = exp2f(sv[c][r] - m[r]);
            sv[c][r] = p;
            lsum[r] += p;
        }
#pragma unroll
    for (int mask = 1; mask < 16; mask <<= 1)
#pragma unroll
        for (int r = 0; r < 4; ++r) lsum[r] += __shfl_xor(lsum[r], mask, 64);
    if (l15 == 0)
#pragma unroll
        for (int r = 0; r < 4; ++r) ll[wn][lg * 4 + r] = lsum[r];
    __syncthreads();
    float invl[4];
#pragma unroll
    for (int r = 0; r < 4; ++r) {
        int row = lg * 4 + r;
        invl[r] = 1.0f / (ll[0][row] + ll[1][row] + ll[2][row] + ll[3][row]);
    }

    // ---- fused PV + avg RMW (double-buffered, 1 barrier/chunk) -------------
    const ushort* vtb = Vt + ((size_t)bh * DKn + wn * 16 + l15) * Ln;
    float* avgrow = avg + ((size_t)bh * Ln + i0) * Ln;   // [16][1024] slice
    f32x4 acco = {};

#define STAGE_P(cc, sb)                                                       \
    _Pragma("unroll")                                                         \
    for (int r = 0; r < 4; ++r) {                                             \
        int row = lg * 4 + r;                                                 \
        float p = sv[cc][r] * invl[r];                                        \
        ushort ph = f2b(p);                                                   \
        int byteo = row * 128 + (((wn * 16 + l15) * 2) ^ ((row & 7) << 4));   \
        *(ushort*)((char*)Ps[sb] + byteo) = ph;                               \
        *(ushort*)((char*)Pl[sb] + byteo) = f2b(p - b2f(ph));                 \
    }

    STAGE_P(0, 0)
#pragma unroll
    for (int c = 0; c < 16; ++c) {
        const int cb = c & 1;
        __syncthreads();   // buf[cb] ready; prior reads of buf[cb^1] done
        // avg RMW prefetch: issued post-barrier, consumed at chunk end
        float aold[4];
        if (!first) {
#pragma unroll
            for (int r = 0; r < 4; ++r)
                aold[r] = avgrow[(size_t)(lg * 4 + r) * Ln + c * 64 + wn * 16 + l15];
        }
        if (c < 15) { STAGE_P(c + 1, cb ^ 1) }
        bf16x8 v0 = *(const bf16x8*)(vtb + c * 64 + lg * 8);
        bf16x8 v1 = *(const bf16x8*)(vtb + c * 64 + 32 + lg * 8);
        bf16x8 pbh[2], pbl[2];
#pragma unroll
        for (int kc = 0; kc < 2; ++kc) {
            int byteo = l15 * 128 + (((kc * 4 + lg) * 16) ^ ((l15 & 7) << 4));
            pbh[kc] = *(const bf16x8*)((char*)Ps[cb] + byteo);
            pbl[kc] = *(const bf16x8*)((char*)Pl[cb] + byteo);
        }
        acco = __builtin_amdgcn_mfma_f32_16x16x32_bf16(v0, pbh[0], acco, 0, 0, 0);
        acco = __builtin_amdgcn_mfma_f32_16x16x32_bf16(v1, pbh[1], acco, 0, 0, 0);
        acco = __builtin_amdgcn_mfma_f32_16x16x32_bf16(v0, pbl[0], acco, 0, 0, 0);
        acco = __builtin_amdgcn_mfma_f32_16x16x32_bf16(v1, pbl[1], acco, 0, 0, 0);
        // avg store: recompute p in-register (1 mul), add prefetched old
#pragma unroll
        for (int r = 0; r < 4; ++r) {
            float v = 0.25f * sv[c][r] * invl[r];
            if (!first) v += aold[r];
            avgrow[(size_t)(lg * 4 + r) * Ln + c * 64 + wn * 16 + l15] = v;
        }
    }
#undef STAGE_P

    // O^T[d = wn*16+lg*4+r][qrow = l15] -> ctx[i0+l15][hh*64 + d]
    {
        uint lo = (uint)f2b(acco[0]) | ((uint)f2b(acco[1]) << 16);
        uint hi = (uint)f2b(acco[2]) | ((uint)f2b(acco[3]) << 16);
        uint2 pk = make_uint2(lo, hi);
        *(uint2*)&ctx[(size_t)(b * Ln + i0 + l15) * Dn + hh * DKn + wn * 16 + lg * 4] = pk;
    }
}

// ---------------------------------------------------------------------------
__global__ __launch_bounds__(256) void layernorm_k(const ushort* __restrict__ X,
                                                   const float* __restrict__ g,
                                                   const float* __restrict__ bta,
                                                   ushort* __restrict__ Y) {
    int w = threadIdx.x >> 6, lane = threadIdx.x & 63;
    int row = blockIdx.x * 4 + w;
    const ushort* xr = X + (size_t)row * Dn;
    float x[4];
#pragma unroll
    for (int ii = 0; ii < 4; ++ii) x[ii] = b2f(xr[lane + 64 * ii]);
    float s = x[0] + x[1] + x[2] + x[3];
#pragma unroll
    for (int m = 1; m < 64; m <<= 1) s += __shfl_xor(s, m, 64);
    float mu = s * (1.0f / 256.0f);
    float vs = 0.f;
#pragma unroll
    for (int ii = 0; ii < 4; ++ii) {
        float d = x[ii] - mu;
        vs += d * d;
    }
#pragma unroll
    for (int m = 1; m < 64; m <<= 1) vs += __shfl_xor(vs, m, 64);
    float rs = rsqrtf(vs * (1.0f / 256.0f) + 1e-5f);
#pragma unroll
    for (int ii = 0; ii < 4; ++ii) {
        int d = lane + 64 * ii;
        Y[(size_t)row * Dn + d] = f2b((x[ii] - mu) * rs * g[d] + bta[d]);
    }
}

// ---------------------------------------------------------------------------
__global__ __launch_bounds__(256) void mean_part_k(const ushort* __restrict__ Hb,
                                                   float* __restrict__ part) {
    int blk = blockIdx.x;            // 64 = 4 b x 16 groups
    int b = blk >> 4, g = blk & 15;
    int d = threadIdx.x;
    float s = 0.f;
#pragma unroll
    for (int r = 0; r < 64; ++r)
        s += b2f(Hb[(size_t)(b * Ln + g * 64 + r) * Dn + d]);
    part[(size_t)blk * Dn + d] = s;
}
__global__ __launch_bounds__(256) void mean_final_k(const float* __restrict__ part,
                                                    float* __restrict__ out) {
    int b = blockIdx.x, d = threadIdx.x;
    float s = 0.f;
#pragma unroll
    for (int g = 0; g < 16; ++g) s += part[(size_t)(b * 16 + g) * Dn + d];
    out[b * Dn + d] = s * (1.0f / (float)Ln);
}

// ---------------------------------------------------------------------------
extern "C" void kernel_launch(void* const* d_in, const int* in_sizes, int n_in,
                              void* d_out, int out_size, void* d_ws, size_t ws_size,
                              hipStream_t stream) {
    const float* x    = (const float*)d_in[0];
    const float* emb  = (const float*)d_in[1];
    const float* Wq   = (const float*)d_in[2];
    const float* bq   = (const float*)d_in[3];
    const float* Wk   = (const float*)d_in[4];
    const float* bk   = (const float*)d_in[5];
    const float* Wv   = (const float*)d_in[6];
    const float* bv   = (const float*)d_in[7];
    const float* Wo   = (const float*)d_in[8];
    const float* bo   = (const float*)d_in[9];
    const float* rk   = (const float*)d_in[10];
    const float* rb   = (const float*)d_in[11];
    const float* ln1g = (const float*)d_in[12];
    const float* ln1b = (const float*)d_in[13];
    const float* W1   = (const float*)d_in[14];
    const float* b1   = (const float*)d_in[15];
    const float* W2   = (const float*)d_in[16];
    const float* b2   = (const float*)d_in[17];
    const float* ln2g = (const float*)d_in[18];
    const float* ln2b = (const float*)d_in[19];

    float* out = (float*)d_out;
    float* avg = out + Bn * Dn;

    char* ws = (char*)d_ws;
    const size_t MB = 1024 * 1024;
    ushort* hb   = (ushort*)(ws);             // 2 MB
    ushort* qkvb = (ushort*)(ws + 2 * MB);    // 6 MB
    ushort* ctxb = (ushort*)(ws + 8 * MB);    // 2 MB
    ushort* t1   = (ushort*)(ws + 10 * MB);   // 2 MB
    ushort* ffb  = (ushort*)(ws + 12 * MB);   // 8 MB
    ushort* qkvT = (ushort*)(ws + 20 * MB);   // 1.5 MB
    ushort* WoT  = (ushort*)(ws + 22 * MB);   // 0.5 MB
    ushort* W1T  = (ushort*)(ws + 23 * MB);   // 2 MB
    ushort* W2T  = (ushort*)(ws + 25 * MB);   // 2 MB
    float*  bqkv = (float*)(ws + 27 * MB);
    float*  bkT  = (float*)(ws + 27 * MB + 65536);
    float*  bbT  = (float*)(ws + 27 * MB + 131072);
    ushort* Vt   = (ushort*)(ws + 30 * MB);   // 2 MB
    float*  mpart= (float*)(ws + 33 * MB);    // 64 KB

    embed_k<<<NTOK, 256, 0, stream>>>(x, emb, hb);
    relbias_k<<<64, 256, 0, stream>>>(rk, rb, bkT, bbT);
    prep_bias<<<12, 256, 0, stream>>>(bq, bk, bv, bqkv);

    dim3 t88(8, 8, NLn);
    transpose_cvt<<<t88, 256, 0, stream>>>(Wq, qkvT + 0,      256, 256, 65536, 196608);
    transpose_cvt<<<t88, 256, 0, stream>>>(Wk, qkvT + 65536,  256, 256, 65536, 196608);
    transpose_cvt<<<t88, 256, 0, stream>>>(Wv, qkvT + 131072, 256, 256, 65536, 196608);
    transpose_cvt<<<t88, 256, 0, stream>>>(Wo, WoT,           256, 256, 65536, 65536);
    transpose_cvt<<<dim3(32, 8, NLn), 256, 0, stream>>>(W1, W1T, 256, 1024, 262144, 262144);
    transpose_cvt<<<dim3(8, 32, NLn), 256, 0, stream>>>(W2, W2T, 1024, 256, 262144, 262144);

    for (int l = 0; l < NLn; ++l) {
        gemm_mfma<<<dim3(12, 64), 256, 0, stream>>>(
            hb, qkvT + (size_t)l * 196608, bqkv + l * QKVW, qkvb, NTOK, QKVW, Dn, 0);
        transpose_v<<<dim3(32, 16), 256, 0, stream>>>(qkvb, Vt);
        attn_fused<<<1024, 256, 0, stream>>>(
            qkvb, Vt, bkT + l * Hn * Ln, bbT + l * Hn * Ln, ctxb, avg, (l == 0) ? 1 : 0);
        gemm_mfma<<<dim3(4, 64), 256, 0, stream>>>(
            ctxb, WoT + (size_t)l * 65536, bo + l * 256, t1, NTOK, Dn, Dn, 0);
        layernorm_k<<<NTOK / 4, 256, 0, stream>>>(
            t1, ln1g + l * 256, ln1b + l * 256, t1);
        gemm_mfma<<<dim3(16, 64), 256, 0, stream>>>(
            t1, W1T + (size_t)l * 262144, b1 + l * FFn, ffb, NTOK, FFn, Dn, 1);
        gemm_mfma<<<dim3(4, 64), 256, 0, stream>>>(
            ffb, W2T + (size_t)l * 262144, b2 + l * 256, hb, NTOK, Dn, FFn, 0);
        layernorm_k<<<NTOK / 4, 256, 0, stream>>>(
            hb, ln2g + l * 256, ln2b + l * 256, hb);
    }
    mean_part_k<<<64, 256, 0, stream>>>(hb, mpart);
    mean_final_k<<<Bn, 256, 0, stream>>>(mpart, out);
}

// Round 8
// 410.005 us; speedup vs baseline: 3.6756x; 1.0694x over previous
//
#include <hip/hip_runtime.h>
#include <hip/hip_bf16.h>
#include <math.h>

// Problem constants
#define Bn 4
#define Ln 1024
#define Vn 64
#define Dn 256
#define Hn 4
#define DKn 64
#define NLn 4
#define Mn 20
#define FFn 1024
#define NTOK (Bn * Ln)   // 4096
#define QKVW 768         // fused q|k|v width
#define LOG2E 1.4426950408889634f

typedef __attribute__((ext_vector_type(8))) short bf16x8;
typedef __attribute__((ext_vector_type(4))) float f32x4;

__device__ __forceinline__ ushort f2b(float f) {   // fp32 -> bf16 RNE
    uint u = __float_as_uint(f);
    u += 0x7fff + ((u >> 16) & 1);
    return (ushort)(u >> 16);
}
__device__ __forceinline__ float b2f(ushort u) {   // exact
    return __uint_as_float(((uint)u) << 16);
}

// ---------------------------------------------------------------------------
__global__ __launch_bounds__(256) void embed_k(const float* __restrict__ X,
                                               const float* __restrict__ E,
                                               ushort* __restrict__ Hb) {
    __shared__ float xs[Vn];
    int n = blockIdx.x, d = threadIdx.x;
    if (threadIdx.x < Vn) xs[threadIdx.x] = X[n * Vn + threadIdx.x];
    __syncthreads();
    float s = 0.f;
#pragma unroll
    for (int v = 0; v < Vn; ++v) s += xs[v] * E[v * Dn + d];
    Hb[(size_t)n * Dn + d] = f2b(s);
}

// ---------------------------------------------------------------------------
// bias tables, pre-scaled into exp2 domain:
//   bkT = rel_k * 0.125 * log2(e);  bbT = rel_b * log2(e)
__global__ __launch_bounds__(256) void relbias_k(const float* __restrict__ rk,
                                                 const float* __restrict__ rb,
                                                 float* __restrict__ bkT,
                                                 float* __restrict__ bbT) {
    int tid = blockIdx.x * 256 + threadIdx.x;   // < NL*H*1024
    int dist = tid & 1023;
    int hh = (tid >> 10) & 3;
    int l = tid >> 12;
    float dd = (float)dist;
    if (dist > Mn) dd = (float)Mn + log2f((float)(dist - Mn));
    if (dd > 2.0f * Mn) dd = 2.0f * Mn;
    int idx = (int)dd;
    bkT[tid] = rk[(l * (2 * Mn + 1) + idx) * Hn + hh] * 0.125f * LOG2E;
    bbT[tid] = rb[(l * (2 * Mn + 1) + idx) * Hn + hh] * LOG2E;
}

// ---------------------------------------------------------------------------
__global__ __launch_bounds__(256) void prep_bias(const float* __restrict__ bq,
                                                 const float* __restrict__ bk,
                                                 const float* __restrict__ bv,
                                                 float* __restrict__ bqkv) {
    int idx = blockIdx.x * 256 + threadIdx.x;   // < NL*768
    int l = idx / QKVW, r = idx - l * QKVW;
    float v;
    if (r < 256)      v = bq[l * 256 + r];
    else if (r < 512) v = bk[l * 256 + r - 256];
    else              v = bv[l * 256 + r - 512];
    bqkv[idx] = v;
}

// ---------------------------------------------------------------------------
// Weight transpose + fp32->bf16: dst[c][r] = src[r][c]; grid.z = layer.
__global__ __launch_bounds__(256) void transpose_cvt(
    const float* __restrict__ src, ushort* __restrict__ dst,
    int R, int C, int srcLS, int dstLS) {
    __shared__ float s[32][33];
    src += (size_t)blockIdx.z * srcLS;
    dst += (size_t)blockIdx.z * dstLS;
    int r0 = blockIdx.y * 32, c0 = blockIdx.x * 32;
    int tx = threadIdx.x & 31, ty = threadIdx.x >> 5;
#pragma unroll
    for (int ii = 0; ii < 4; ++ii)
        s[ty + 8 * ii][tx] = src[(size_t)(r0 + ty + 8 * ii) * C + c0 + tx];
    __syncthreads();
#pragma unroll
    for (int ii = 0; ii < 4; ++ii)
        dst[(size_t)(c0 + ty + 8 * ii) * R + r0 + tx] = f2b(s[tx][ty + 8 * ii]);
}

// ---------------------------------------------------------------------------
// V transpose per (b,h): Vt[bh][d][j] = qkvb[b*L+j][512 + h*64 + d]
__global__ __launch_bounds__(256) void transpose_v(const ushort* __restrict__ qkv,
                                                   ushort* __restrict__ Vt) {
    __shared__ ushort s[32][65];
    int j0 = blockIdx.x * 32;
    int bh = blockIdx.y;
    int b = bh >> 2, hh = bh & 3;
    int t = threadIdx.x;
#pragma unroll
    for (int ii = 0; ii < 8; ++ii) {
        int e = t + 256 * ii;          // 2048 = 32 j x 64 d
        int jr = e >> 6, dc = e & 63;
        s[jr][dc] = qkv[(size_t)(b * Ln + j0 + jr) * QKVW + 2 * Dn + hh * DKn + dc];
    }
    __syncthreads();
#pragma unroll
    for (int ii = 0; ii < 8; ++ii) {
        int e = t + 256 * ii;          // 2048 = 64 d x 32 j
        int dr = e >> 5, jc = e & 31;
        Vt[(size_t)(bh * DKn + dr) * Ln + j0 + jc] = s[jc][dr];
    }
}

// ---------------------------------------------------------------------------
// bf16 MFMA GEMM: C[m][n] = act(sum_k A[m][k]*Bt[n][k] + bias[n]), C bf16.
#define GST 40
__global__ __launch_bounds__(256) void gemm_mfma(
    const ushort* __restrict__ A, const ushort* __restrict__ Bt,
    const float* __restrict__ bias, ushort* __restrict__ C,
    int M, int N, int K, int act) {
    __shared__ __align__(16) ushort As[64 * GST];
    __shared__ __align__(16) ushort Bs[64 * GST];
    int t = threadIdx.x;
    int lane = t & 63, w = t >> 6;
    int wm = w >> 1, wn = w & 1;
    int l15 = lane & 15, lg = lane >> 4;
    int mBase = blockIdx.y * 64, nBase = blockIdx.x * 64;
    int lrow = t >> 2, lkc = (t & 3) * 8;
    const ushort* Ap = A + (size_t)(mBase + lrow) * K + lkc;
    const ushort* Bp = Bt + (size_t)(nBase + lrow) * K + lkc;
    f32x4 acc[2][2] = {};
    for (int k0 = 0; k0 < K; k0 += 32) {
        uint4 av = *(const uint4*)(Ap + k0);
        uint4 bv = *(const uint4*)(Bp + k0);
        __syncthreads();
        *(uint4*)&As[lrow * GST + lkc] = av;
        *(uint4*)&Bs[lrow * GST + lkc] = bv;
        __syncthreads();
        bf16x8 a0 = *(const bf16x8*)&As[(wm * 32 + l15) * GST + lg * 8];
        bf16x8 a1 = *(const bf16x8*)&As[(wm * 32 + 16 + l15) * GST + lg * 8];
        bf16x8 b0 = *(const bf16x8*)&Bs[(wn * 32 + l15) * GST + lg * 8];
        bf16x8 b1 = *(const bf16x8*)&Bs[(wn * 32 + 16 + l15) * GST + lg * 8];
        acc[0][0] = __builtin_amdgcn_mfma_f32_16x16x32_bf16(a0, b0, acc[0][0], 0, 0, 0);
        acc[0][1] = __builtin_amdgcn_mfma_f32_16x16x32_bf16(a0, b1, acc[0][1], 0, 0, 0);
        acc[1][0] = __builtin_amdgcn_mfma_f32_16x16x32_bf16(a1, b0, acc[1][0], 0, 0, 0);
        acc[1][1] = __builtin_amdgcn_mfma_f32_16x16x32_bf16(a1, b1, acc[1][1], 0, 0, 0);
    }
#pragma unroll
    for (int ni = 0; ni < 2; ++ni) {
        int col = nBase + wn * 32 + ni * 16 + l15;
        float bc = bias[col];
#pragma unroll
        for (int mi = 0; mi < 2; ++mi) {
            int rb = mBase + wm * 32 + mi * 16 + lg * 4;
#pragma unroll
            for (int j = 0; j < 4; ++j) {
                float v = acc[mi][ni][j] + bc;
                if (act) v = v * 0.5f * (1.0f + erff(v * 0.7071067811865475f));
                C[(size_t)(rb + j) * N + col] = f2b(v);
            }
        }
    }
}

// ---------------------------------------------------------------------------
// MFMA flash attention. QK: scores in registers (no barriers). PV: each wave
// accumulates a PARTIAL O over its own 16-col k-slice -> the P transpose is
// wave-private LDS (no barriers at all in the loop; compiler lgkmcnt handles
// same-wave RAW). One final barrier + LDS reduce sums the 4 partial O's.
// avg RMW free-flows through the unrolled barrier-free loop.
#define PWST 40   // ushort stride per P row (80B, 16B-aligned)
__global__ __launch_bounds__(256) void attn_fused(
    const ushort* __restrict__ qkv, const ushort* __restrict__ Vt,
    const float* __restrict__ bkTab, const float* __restrict__ bbTab,
    ushort* __restrict__ ctx, float* __restrict__ avg, int first) {
    __shared__ float bk_l[Ln];
    __shared__ float bb_l[Ln];
    __shared__ __align__(16) ushort Pw[4][2][16 * PWST];  // [wave][hi/lo][i][k32]
    __shared__ float mm[4][16];
    __shared__ float ll[4][16];
    __shared__ float Opart[4][1024];                      // [wave][d*16+i]

    int t = threadIdx.x;
    int lane = t & 63, wn = t >> 6;       // wave = k-slice quarter
    int l15 = lane & 15, lg = lane >> 4;

    int bid = blockIdx.x;
    int xcd = bid & 7, sub = bid >> 3;    // sub in [0,128)
    int bh = xcd * 2 + (sub >> 6);
    int q = sub & 63;
    int b = bh >> 2, hh = bh & 3;
    int i0 = q * 16;

#pragma unroll
    for (int ii = 0; ii < 4; ++ii) {
        bk_l[t + 256 * ii] = bkTab[hh * Ln + t + 256 * ii];
        bb_l[t + 256 * ii] = bbTab[hh * Ln + t + 256 * ii];
    }
    __syncthreads();

    // Q fragment (A-operand): row = i0 + l15, k = lg*8 (+32)
    bf16x8 qa0, qa1;
    {
        const ushort* qp = qkv + (size_t)(b * Ln + i0 + l15) * QKVW + hh * DKn;
        qa0 = *(const bf16x8*)(qp + lg * 8);
        qa1 = *(const bf16x8*)(qp + 32 + lg * 8);
    }

    const ushort* kbase = qkv + (size_t)(b * Ln) * QKVW + Dn + hh * DKn;

    // ---- QK pass: S kept in registers (fully unrolled, barrier-free) -------
    f32x4 sv[16];
    float m[4] = {-1e30f, -1e30f, -1e30f, -1e30f};
#pragma unroll
    for (int c = 0; c < 16; ++c) {
        const ushort* kp = kbase + (size_t)(c * 64 + wn * 16 + l15) * QKVW;
        bf16x8 k0 = *(const bf16x8*)(kp + lg * 8);
        bf16x8 k1 = *(const bf16x8*)(kp + 32 + lg * 8);
        f32x4 acc = {};
        acc = __builtin_amdgcn_mfma_f32_16x16x32_bf16(qa0, k0, acc, 0, 0, 0);
        acc = __builtin_amdgcn_mfma_f32_16x16x32_bf16(qa1, k1, acc, 0, 0, 0);
        int j = c * 64 + wn * 16 + l15;
#pragma unroll
        for (int r = 0; r < 4; ++r) {
            int i = i0 + lg * 4 + r;
            int dist = (i > j) ? (i - j) : (j - i);
            float s = acc[r] * bk_l[dist] + bb_l[dist];
            sv[c][r] = s;
            m[r] = fmaxf(m[r], s);
        }
    }
    // merge max over the 16 l15-lanes
#pragma unroll
    for (int mask = 1; mask < 16; mask <<= 1)
#pragma unroll
        for (int r = 0; r < 4; ++r) m[r] = fmaxf(m[r], __shfl_xor(m[r], mask, 64));
    // merge max across the 4 waves
    if (l15 == 0)
#pragma unroll
        for (int r = 0; r < 4; ++r) mm[wn][lg * 4 + r] = m[r];
    __syncthreads();
#pragma unroll
    for (int r = 0; r < 4; ++r) {
        int row = lg * 4 + r;
        m[r] = fmaxf(fmaxf(mm[0][row], mm[1][row]), fmaxf(mm[2][row], mm[3][row]));
    }
    // p_unnorm = exp2(s - m); accumulate row sums
    float lsum[4] = {0.f, 0.f, 0.f, 0.f};
#pragma unroll
    for (int c = 0; c < 16; ++c)
#pragma unroll
        for (int r = 0; r < 4; ++r) {
            float p = exp2f(sv[c][r] - m[r]);
            sv[c][r] = p;
            lsum[r] += p;
        }
#pragma unroll
    for (int mask = 1; mask < 16; mask <<= 1)
#pragma unroll
        for (int r = 0; r < 4; ++r) lsum[r] += __shfl_xor(lsum[r], mask, 64);
    if (l15 == 0)
#pragma unroll
        for (int r = 0; r < 4; ++r) ll[wn][lg * 4 + r] = lsum[r];
    __syncthreads();
    float invl[4];
#pragma unroll
    for (int r = 0; r < 4; ++r) {
        int row = lg * 4 + r;
        invl[r] = 1.0f / (ll[0][row] + ll[1][row] + ll[2][row] + ll[3][row]);
    }

    // ---- PV partial-O + avg RMW: ZERO barriers ------------------------------
    // Wave wn: k-slice cols {c*64 + wn*16 + 0..15}. Pairs of chunks -> K=32.
    const ushort* vbase = Vt + (size_t)bh * DKn * Ln;       // [64 d][Ln k]
    float* avgrow = avg + ((size_t)bh * Ln + i0) * Ln;      // [16 i][Ln j]
    f32x4 acco[4] = {};
#pragma unroll
    for (int p = 0; p < 8; ++p) {
        const int c0 = 2 * p, c1 = 2 * p + 1;
        // avg old values (RMW read) — consumed late, pipelines freely
        float aold[2][4];
        if (!first) {
#pragma unroll
            for (int cc = 0; cc < 2; ++cc)
#pragma unroll
                for (int r = 0; r < 4; ++r)
                    aold[cc][r] = avgrow[(size_t)(lg * 4 + r) * Ln +
                                         (c0 + cc) * 64 + wn * 16 + l15];
        }
        // stage P (hi/lo) into wave-private LDS; keep pnorm for avg store
        float pn[2][4];
#pragma unroll
        for (int cc = 0; cc < 2; ++cc)
#pragma unroll
            for (int r = 0; r < 4; ++r) {
                float pv = sv[c0 + cc][r] * invl[r];
                pn[cc][r] = pv;
                ushort ph = f2b(pv);
                int off = (lg * 4 + r) * PWST + cc * 16 + l15;
                Pw[wn][0][off] = ph;
                Pw[wn][1][off] = f2b(pv - b2f(ph));
            }
        // V A-fragments: 4 d-groups; lane's k-octet maps lg -> chunk/col
        int kcol = (lg < 2 ? c0 : c1) * 64 + wn * 16 + (lg & 1) * 8;
        bf16x8 va0 = *(const bf16x8*)(vbase + (size_t)(0 * 16 + l15) * Ln + kcol);
        bf16x8 va1 = *(const bf16x8*)(vbase + (size_t)(1 * 16 + l15) * Ln + kcol);
        bf16x8 va2 = *(const bf16x8*)(vbase + (size_t)(2 * 16 + l15) * Ln + kcol);
        bf16x8 va3 = *(const bf16x8*)(vbase + (size_t)(3 * 16 + l15) * Ln + kcol);
        // B fragments from own LDS (same-wave RAW: compiler lgkmcnt)
        bf16x8 pbh = *(const bf16x8*)&Pw[wn][0][l15 * PWST + lg * 8];
        bf16x8 pbl = *(const bf16x8*)&Pw[wn][1][l15 * PWST + lg * 8];
        acco[0] = __builtin_amdgcn_mfma_f32_16x16x32_bf16(va0, pbh, acco[0], 0, 0, 0);
        acco[1] = __builtin_amdgcn_mfma_f32_16x16x32_bf16(va1, pbh, acco[1], 0, 0, 0);
        acco[2] = __builtin_amdgcn_mfma_f32_16x16x32_bf16(va2, pbh, acco[2], 0, 0, 0);
        acco[3] = __builtin_amdgcn_mfma_f32_16x16x32_bf16(va3, pbh, acco[3], 0, 0, 0);
        acco[0] = __builtin_amdgcn_mfma_f32_16x16x32_bf16(va0, pbl, acco[0], 0, 0, 0);
        acco[1] = __builtin_amdgcn_mfma_f32_16x16x32_bf16(va1, pbl, acco[1], 0, 0, 0);
        acco[2] = __builtin_amdgcn_mfma_f32_16x16x32_bf16(va2, pbl, acco[2], 0, 0, 0);
        acco[3] = __builtin_amdgcn_mfma_f32_16x16x32_bf16(va3, pbl, acco[3], 0, 0, 0);
        // avg stores (coalesced 64B per 16-lane group)
#pragma unroll
        for (int cc = 0; cc < 2; ++cc)
#pragma unroll
            for (int r = 0; r < 4; ++r) {
                float v = 0.25f * pn[cc][r];
                if (!first) v += aold[cc][r];
                avgrow[(size_t)(lg * 4 + r) * Ln + (c0 + cc) * 64 + wn * 16 + l15] = v;
            }
    }

    // ---- reduce partial O across the 4 waves (single barrier) ---------------
#pragma unroll
    for (int dg = 0; dg < 4; ++dg)
#pragma unroll
        for (int r = 0; r < 4; ++r)
            Opart[wn][(dg * 16 + lg * 4 + r) * 16 + l15] = acco[dg][r];
    __syncthreads();
#pragma unroll
    for (int k = 0; k < 4; ++k) {
        int idx = t + 256 * k;          // idx = d*16 + i
        float v = Opart[0][idx] + Opart[1][idx] + Opart[2][idx] + Opart[3][idx];
        int dd = idx >> 4, ii = idx & 15;
        ctx[(size_t)(b * Ln + i0 + ii) * Dn + hh * DKn + dd] = f2b(v);
    }
}

// ---------------------------------------------------------------------------
__global__ __launch_bounds__(256) void layernorm_k(const ushort* __restrict__ X,
                                                   const float* __restrict__ g,
                                                   const float* __restrict__ bta,
                                                   ushort* __restrict__ Y) {
    int w = threadIdx.x >> 6, lane = threadIdx.x & 63;
    int row = blockIdx.x * 4 + w;
    const ushort* xr = X + (size_t)row * Dn;
    float x[4];
#pragma unroll
    for (int ii = 0; ii < 4; ++ii) x[ii] = b2f(xr[lane + 64 * ii]);
    float s = x[0] + x[1] + x[2] + x[3];
#pragma unroll
    for (int m = 1; m < 64; m <<= 1) s += __shfl_xor(s, m, 64);
    float mu = s * (1.0f / 256.0f);
    float vs = 0.f;
#pragma unroll
    for (int ii = 0; ii < 4; ++ii) {
        float d = x[ii] - mu;
        vs += d * d;
    }
#pragma unroll
    for (int m = 1; m < 64; m <<= 1) vs += __shfl_xor(vs, m, 64);
    float rs = rsqrtf(vs * (1.0f / 256.0f) + 1e-5f);
#pragma unroll
    for (int ii = 0; ii < 4; ++ii) {
        int d = lane + 64 * ii;
        Y[(size_t)row * Dn + d] = f2b((x[ii] - mu) * rs * g[d] + bta[d]);
    }
}

// ---------------------------------------------------------------------------
__global__ __launch_bounds__(256) void mean_part_k(const ushort* __restrict__ Hb,
                                                   float* __restrict__ part) {
    int blk = blockIdx.x;            // 64 = 4 b x 16 groups
    int b = blk >> 4, g = blk & 15;
    int d = threadIdx.x;
    float s = 0.f;
#pragma unroll
    for (int r = 0; r < 64; ++r)
        s += b2f(Hb[(size_t)(b * Ln + g * 64 + r) * Dn + d]);
    part[(size_t)blk * Dn + d] = s;
}
__global__ __launch_bounds__(256) void mean_final_k(const float* __restrict__ part,
                                                    float* __restrict__ out) {
    int b = blockIdx.x, d = threadIdx.x;
    float s = 0.f;
#pragma unroll
    for (int g = 0; g < 16; ++g) s += part[(size_t)(b * 16 + g) * Dn + d];
    out[b * Dn + d] = s * (1.0f / (float)Ln);
}

// ---------------------------------------------------------------------------
extern "C" void kernel_launch(void* const* d_in, const int* in_sizes, int n_in,
                              void* d_out, int out_size, void* d_ws, size_t ws_size,
                              hipStream_t stream) {
    const float* x    = (const float*)d_in[0];
    const float* emb  = (const float*)d_in[1];
    const float* Wq   = (const float*)d_in[2];
    const float* bq   = (const float*)d_in[3];
    const float* Wk   = (const float*)d_in[4];
    const float* bk   = (const float*)d_in[5];
    const float* Wv   = (const float*)d_in[6];
    const float* bv   = (const float*)d_in[7];
    const float* Wo   = (const float*)d_in[8];
    const float* bo   = (const float*)d_in[9];
    const float* rk   = (const float*)d_in[10];
    const float* rb   = (const float*)d_in[11];
    const float* ln1g = (const float*)d_in[12];
    const float* ln1b = (const float*)d_in[13];
    const float* W1   = (const float*)d_in[14];
    const float* b1   = (const float*)d_in[15];
    const float* W2   = (const float*)d_in[16];
    const float* b2   = (const float*)d_in[17];
    const float* ln2g = (const float*)d_in[18];
    const float* ln2b = (const float*)d_in[19];

    float* out = (float*)d_out;
    float* avg = out + Bn * Dn;

    char* ws = (char*)d_ws;
    const size_t MB = 1024 * 1024;
    ushort* hb   = (ushort*)(ws);             // 2 MB
    ushort* qkvb = (ushort*)(ws + 2 * MB);    // 6 MB
    ushort* ctxb = (ushort*)(ws + 8 * MB);    // 2 MB
    ushort* t1   = (ushort*)(ws + 10 * MB);   // 2 MB
    ushort* ffb  = (ushort*)(ws + 12 * MB);   // 8 MB
    ushort* qkvT = (ushort*)(ws + 20 * MB);   // 1.5 MB
    ushort* WoT  = (ushort*)(ws + 22 * MB);   // 0.5 MB
    ushort* W1T  = (ushort*)(ws + 23 * MB);   // 2 MB
    ushort* W2T  = (ushort*)(ws + 25 * MB);   // 2 MB
    float*  bqkv = (float*)(ws + 27 * MB);
    float*  bkT  = (float*)(ws + 27 * MB + 65536);
    float*  bbT  = (float*)(ws + 27 * MB + 131072);
    ushort* Vt   = (ushort*)(ws + 30 * MB);   // 2 MB
    float*  mpart= (float*)(ws + 33 * MB);    // 64 KB

    embed_k<<<NTOK, 256, 0, stream>>>(x, emb, hb);
    relbias_k<<<64, 256, 0, stream>>>(rk, rb, bkT, bbT);
    prep_bias<<<12, 256, 0, stream>>>(bq, bk, bv, bqkv);

    dim3 t88(8, 8, NLn);
    transpose_cvt<<<t88, 256, 0, stream>>>(Wq, qkvT + 0,      256, 256, 65536, 196608);
    transpose_cvt<<<t88, 256, 0, stream>>>(Wk, qkvT + 65536,  256, 256, 65536, 196608);
    transpose_cvt<<<t88, 256, 0, stream>>>(Wv, qkvT + 131072, 256, 256, 65536, 196608);
    transpose_cvt<<<t88, 256, 0, stream>>>(Wo, WoT,           256, 256, 65536, 65536);
    transpose_cvt<<<dim3(32, 8, NLn), 256, 0, stream>>>(W1, W1T, 256, 1024, 262144, 262144);
    transpose_cvt<<<dim3(8, 32, NLn), 256, 0, stream>>>(W2, W2T, 1024, 256, 262144, 262144);

    for (int l = 0; l < NLn; ++l) {
        gemm_mfma<<<dim3(12, 64), 256, 0, stream>>>(
            hb, qkvT + (size_t)l * 196608, bqkv + l * QKVW, qkvb, NTOK, QKVW, Dn, 0);
        transpose_v<<<dim3(32, 16), 256, 0, stream>>>(qkvb, Vt);
        attn_fused<<<1024, 256, 0, stream>>>(
            qkvb, Vt, bkT + l * Hn * Ln, bbT + l * Hn * Ln, ctxb, avg, (l == 0) ? 1 : 0);
        gemm_mfma<<<dim3(4, 64), 256, 0, stream>>>(
            ctxb, WoT + (size_t)l * 65536, bo + l * 256, t1, NTOK, Dn, Dn, 0);
        layernorm_k<<<NTOK / 4, 256, 0, stream>>>(
            t1, ln1g + l * 256, ln1b + l * 256, t1);
        gemm_mfma<<<dim3(16, 64), 256, 0, stream>>>(
            t1, W1T + (size_t)l * 262144, b1 + l * FFn, ffb, NTOK, FFn, Dn, 1);
        gemm_mfma<<<dim3(4, 64), 256, 0, stream>>>(
            ffb, W2T + (size_t)l * 262144, b2 + l * 256, hb, NTOK, Dn, FFn, 0);
        layernorm_k<<<NTOK / 4, 256, 0, stream>>>(
            hb, ln2g + l * 256, ln2b + l * 256, hb);
    }
    mean_part_k<<<64, 256, 0, stream>>>(hb, mpart);
    mean_final_k<<<Bn, 256, 0, stream>>>(mpart, out);
}